// Round 1
// baseline (188.070 us; speedup 1.0000x reference)
//
#include <hip/hip_runtime.h>
#include <hip/hip_bf16.h>
#include <stdint.h>

#define T_TOK 2048
#define DHID  1024
#define NEXP  16
#define MR    256
#define MS    512
#define CAP   512   // max tokens per routed expert (mean 256, std ~16)
#define BK    64
#define LDA   72    // padded LDS row stride in bf16 (bank-stride 4 -> 2-way, free)

typedef float  f32x4  __attribute__((ext_vector_type(4)));
typedef __bf16 bf16x8 __attribute__((ext_vector_type(8)));

__device__ __forceinline__ ushort f2bf(float f) {
  uint32_t u = __float_as_uint(f);
  u = (u + 0x7fffu + ((u >> 16) & 1u)) >> 16;
  return (ushort)u;
}

// ---------------- zero the per-expert counters ----------------
__global__ void k_zero(int* c) {
  if (threadIdx.x < NEXP) c[threadIdx.x] = 0;
}

// ---------------- convert x to bf16 + fp32 router + expert lists ----------------
__global__ __launch_bounds__(256) void k_prep(
    const float* __restrict__ x, const float* __restrict__ rw,
    ushort* __restrict__ xb, int* __restrict__ cnt,
    int* __restrict__ ltok, float* __restrict__ lw)
{
  const int wave = threadIdx.x >> 6, lane = threadIdx.x & 63;
  const int t = blockIdx.x * 4 + wave;
  const float* xp = x + (size_t)t * DHID;

  float acc[NEXP];
#pragma unroll
  for (int e = 0; e < NEXP; e++) acc[e] = 0.f;

#pragma unroll
  for (int i = 0; i < 4; i++) {
    const int d = i * 256 + lane * 4;
    float4 v = *(const float4*)&xp[d];
    ushort4 o; o.x = f2bf(v.x); o.y = f2bf(v.y); o.z = f2bf(v.z); o.w = f2bf(v.w);
    *(ushort4*)&xb[(size_t)t * DHID + d] = o;
    float xv[4] = {v.x, v.y, v.z, v.w};
#pragma unroll
    for (int j = 0; j < 4; j++) {
      const float* rrow = rw + (size_t)(d + j) * NEXP;
#pragma unroll
      for (int e = 0; e < NEXP; e++) acc[e] += xv[j] * rrow[e];
    }
  }
  // wave butterfly reduce (all lanes end with totals)
#pragma unroll
  for (int off = 32; off >= 1; off >>= 1) {
#pragma unroll
    for (int e = 0; e < NEXP; e++) acc[e] += __shfl_xor(acc[e], off, 64);
  }
  if (lane == 0) {
    float m = acc[0];
#pragma unroll
    for (int e = 1; e < NEXP; e++) m = fmaxf(m, acc[e]);
    float p[NEXP], Z = 0.f;
#pragma unroll
    for (int e = 0; e < NEXP; e++) { p[e] = __expf(acc[e] - m); Z += p[e]; }
    const float inv = 1.f / Z;
    int i1 = 0; float p1 = p[0] * inv;
    for (int e = 1; e < NEXP; e++) { float pe = p[e] * inv; if (pe > p1) { p1 = pe; i1 = e; } }
    int i2 = -1; float p2 = -1.f;
    for (int e = 0; e < NEXP; e++) { if (e == i1) continue; float pe = p[e] * inv; if (pe > p2) { p2 = pe; i2 = e; } }
    const float denom = p1 + p2 + 1e-9f;
    const float w1 = p1 / denom, w2 = p2 / denom;
    int pos1 = atomicAdd(&cnt[i1], 1);
    if (pos1 < CAP) { ltok[i1 * CAP + pos1] = t; lw[i1 * CAP + pos1] = w1; }
    int pos2 = atomicAdd(&cnt[i2], 1);
    if (pos2 < CAP) { ltok[i2 * CAP + pos2] = t; lw[i2 * CAP + pos2] = w2; }
  }
}

// ---------------- transpose+convert weights: in [B][R][C] f32 -> out[b][c][r] bf16 ----------------
// out element index: b*out_batch + c*out_ld + r
__global__ __launch_bounds__(256) void k_transpose(
    const float* __restrict__ in, ushort* __restrict__ out,
    int C, int out_ld, size_t out_batch)
{
  __shared__ float t_sh[64][65];
  const int b = blockIdx.z;
  const int r0 = blockIdx.y * 64, c0 = blockIdx.x * 64;
  const float* ip = in + (size_t)b * (size_t)gridDim.y * 64 * C;
  const int tr = threadIdx.x >> 4;          // 0..15
  const int tc = (threadIdx.x & 15) * 4;    // 0..60
#pragma unroll
  for (int p = 0; p < 4; p++) {
    float4 v = *(const float4*)&ip[(size_t)(r0 + tr + p * 16) * C + c0 + tc];
    t_sh[tr + p * 16][tc + 0] = v.x; t_sh[tr + p * 16][tc + 1] = v.y;
    t_sh[tr + p * 16][tc + 2] = v.z; t_sh[tr + p * 16][tc + 3] = v.w;
  }
  __syncthreads();
  ushort* op = out + (size_t)b * out_batch;
#pragma unroll
  for (int p = 0; p < 4; p++) {
    const int cc = tr + p * 16;
    ushort4 o;
    o.x = f2bf(t_sh[tc + 0][cc]); o.y = f2bf(t_sh[tc + 1][cc]);
    o.z = f2bf(t_sh[tc + 2][cc]); o.w = f2bf(t_sh[tc + 3][cc]);
    *(ushort4*)&op[(size_t)(c0 + cc) * out_ld + r0 + tc] = o;
  }
}

// ---------------- shared experts: G=X@Wg, U=X@Wu, h = silu(G)*U -> h_s[t][e*512+m] ----------------
__global__ __launch_bounds__(256) void k_up_shared(
    const ushort* __restrict__ xb, const ushort* __restrict__ wgT,
    const ushort* __restrict__ wuT, ushort* __restrict__ h_s)
{
  __shared__ ushort a_sh[64 * LDA], g_sh[64 * LDA], u_sh[64 * LDA];
  const int t0 = blockIdx.x * 64;
  const int gn0 = blockIdx.y * 64;      // over 2*MS = 1024 (e*512+m)
  const int tid = threadIdx.x, wave = tid >> 6, lane = tid & 63;
  const int srow = tid >> 2, sseg = tid & 3;

  const ushort* Ab = xb  + (size_t)t0  * DHID;
  const ushort* Gb = wgT + (size_t)gn0 * DHID;
  const ushort* Ub = wuT + (size_t)gn0 * DHID;

  f32x4 accg[4] = {}; f32x4 accu[4] = {};
  for (int k0 = 0; k0 < DHID; k0 += BK) {
    __syncthreads();
    const size_t so = (size_t)srow * DHID + k0;
    *(uint4*)&a_sh[srow * LDA + sseg * 8]       = *(const uint4*)&Ab[so + sseg * 8];
    *(uint4*)&a_sh[srow * LDA + (sseg + 4) * 8] = *(const uint4*)&Ab[so + (sseg + 4) * 8];
    *(uint4*)&g_sh[srow * LDA + sseg * 8]       = *(const uint4*)&Gb[so + sseg * 8];
    *(uint4*)&g_sh[srow * LDA + (sseg + 4) * 8] = *(const uint4*)&Gb[so + (sseg + 4) * 8];
    *(uint4*)&u_sh[srow * LDA + sseg * 8]       = *(const uint4*)&Ub[so + sseg * 8];
    *(uint4*)&u_sh[srow * LDA + (sseg + 4) * 8] = *(const uint4*)&Ub[so + (sseg + 4) * 8];
    __syncthreads();
    const int ar = wave * 16 + (lane & 15), bc = lane & 15, k8 = (lane >> 4) * 8;
#pragma unroll
    for (int kk = 0; kk < BK; kk += 32) {
      bf16x8 af = *(const bf16x8*)&a_sh[ar * LDA + kk + k8];
#pragma unroll
      for (int nt = 0; nt < 4; nt++) {
        bf16x8 gf = *(const bf16x8*)&g_sh[(nt * 16 + bc) * LDA + kk + k8];
        bf16x8 uf = *(const bf16x8*)&u_sh[(nt * 16 + bc) * LDA + kk + k8];
        accg[nt] = __builtin_amdgcn_mfma_f32_16x16x32_bf16(af, gf, accg[nt], 0, 0, 0);
        accu[nt] = __builtin_amdgcn_mfma_f32_16x16x32_bf16(af, uf, accu[nt], 0, 0, 0);
      }
    }
  }
  const int trow = t0 + wave * 16 + ((lane >> 4) << 2);
#pragma unroll
  for (int nt = 0; nt < 4; nt++) {
    const int n = gn0 + nt * 16 + (lane & 15);
#pragma unroll
    for (int j = 0; j < 4; j++) {
      float g = accg[nt][j], u = accu[nt][j];
      float h = (g / (1.f + __expf(-g))) * u;
      h_s[(size_t)(trow + j) * DHID + n] = f2bf(h);
    }
  }
}

// ---------------- routed experts up: gathered rows, h = silu(g)*u*w -> h_r[e][slot][m] ----------------
__global__ __launch_bounds__(256) void k_up_routed(
    const ushort* __restrict__ xb, const ushort* __restrict__ wgT,
    const ushort* __restrict__ wuT, const int* __restrict__ cnt,
    const int* __restrict__ ltok, const float* __restrict__ lw,
    ushort* __restrict__ h_r)
{
  __shared__ ushort a_sh[64 * LDA], g_sh[64 * LDA], u_sh[64 * LDA];
  const int e = blockIdx.z;
  const int c = cnt[e];
  const int s0 = blockIdx.x * 64;
  if (s0 >= c) return;
  const int m0 = blockIdx.y * 64;       // over MR=256
  const int tid = threadIdx.x, wave = tid >> 6, lane = tid & 63;
  const int srow = tid >> 2, sseg = tid & 3;

  const int stok = (s0 + srow < c) ? ltok[e * CAP + s0 + srow] : -1;
  const ushort* Gb = wgT + ((size_t)e * MR + m0) * DHID;
  const ushort* Ub = wuT + ((size_t)e * MR + m0) * DHID;

  f32x4 accg[4] = {}; f32x4 accu[4] = {};
  for (int k0 = 0; k0 < DHID; k0 += BK) {
    __syncthreads();
    uint4 av0 = {0, 0, 0, 0}, av1 = {0, 0, 0, 0};
    if (stok >= 0) {
      const size_t xo = (size_t)stok * DHID + k0;
      av0 = *(const uint4*)&xb[xo + sseg * 8];
      av1 = *(const uint4*)&xb[xo + (sseg + 4) * 8];
    }
    *(uint4*)&a_sh[srow * LDA + sseg * 8]       = av0;
    *(uint4*)&a_sh[srow * LDA + (sseg + 4) * 8] = av1;
    const size_t so = (size_t)srow * DHID + k0;
    *(uint4*)&g_sh[srow * LDA + sseg * 8]       = *(const uint4*)&Gb[so + sseg * 8];
    *(uint4*)&g_sh[srow * LDA + (sseg + 4) * 8] = *(const uint4*)&Gb[so + (sseg + 4) * 8];
    *(uint4*)&u_sh[srow * LDA + sseg * 8]       = *(const uint4*)&Ub[so + sseg * 8];
    *(uint4*)&u_sh[srow * LDA + (sseg + 4) * 8] = *(const uint4*)&Ub[so + (sseg + 4) * 8];
    __syncthreads();
    const int ar = wave * 16 + (lane & 15), bc = lane & 15, k8 = (lane >> 4) * 8;
#pragma unroll
    for (int kk = 0; kk < BK; kk += 32) {
      bf16x8 af = *(const bf16x8*)&a_sh[ar * LDA + kk + k8];
#pragma unroll
      for (int nt = 0; nt < 4; nt++) {
        bf16x8 gf = *(const bf16x8*)&g_sh[(nt * 16 + bc) * LDA + kk + k8];
        bf16x8 uf = *(const bf16x8*)&u_sh[(nt * 16 + bc) * LDA + kk + k8];
        accg[nt] = __builtin_amdgcn_mfma_f32_16x16x32_bf16(af, gf, accg[nt], 0, 0, 0);
        accu[nt] = __builtin_amdgcn_mfma_f32_16x16x32_bf16(af, uf, accu[nt], 0, 0, 0);
      }
    }
  }
  const int bc = lane & 15;
#pragma unroll
  for (int j = 0; j < 4; j++) {
    const int slot = s0 + wave * 16 + ((lane >> 4) << 2) + j;
    if (slot < c) {
      const float w = lw[e * CAP + slot];
#pragma unroll
      for (int nt = 0; nt < 4; nt++) {
        float g = accg[nt][j], u = accu[nt][j];
        float h = (g / (1.f + __expf(-g))) * u * w;
        h_r[(size_t)e * CAP * MR + (size_t)slot * MR + m0 + nt * 16 + bc] = f2bf(h);
      }
    }
  }
}

// ---------------- shared down: out = h_s @ wd_cat (K=1024), plain stores ----------------
__global__ __launch_bounds__(256) void k_down_shared(
    const ushort* __restrict__ A, const ushort* __restrict__ BT,
    float* __restrict__ out)
{
  __shared__ ushort a_sh[64 * LDA], b_sh[64 * LDA];
  const int t0 = blockIdx.x * 64, n0 = blockIdx.y * 64;
  const int tid = threadIdx.x, wave = tid >> 6, lane = tid & 63;
  const int srow = tid >> 2, sseg = tid & 3;
  const ushort* Ab = A  + (size_t)t0 * DHID;
  const ushort* Bb = BT + (size_t)n0 * DHID;

  f32x4 acc[4] = {};
  for (int k0 = 0; k0 < DHID; k0 += BK) {
    __syncthreads();
    const size_t so = (size_t)srow * DHID + k0;
    *(uint4*)&a_sh[srow * LDA + sseg * 8]       = *(const uint4*)&Ab[so + sseg * 8];
    *(uint4*)&a_sh[srow * LDA + (sseg + 4) * 8] = *(const uint4*)&Ab[so + (sseg + 4) * 8];
    *(uint4*)&b_sh[srow * LDA + sseg * 8]       = *(const uint4*)&Bb[so + sseg * 8];
    *(uint4*)&b_sh[srow * LDA + (sseg + 4) * 8] = *(const uint4*)&Bb[so + (sseg + 4) * 8];
    __syncthreads();
    const int ar = wave * 16 + (lane & 15), bc = lane & 15, k8 = (lane >> 4) * 8;
#pragma unroll
    for (int kk = 0; kk < BK; kk += 32) {
      bf16x8 af = *(const bf16x8*)&a_sh[ar * LDA + kk + k8];
#pragma unroll
      for (int nt = 0; nt < 4; nt++) {
        bf16x8 bf = *(const bf16x8*)&b_sh[(nt * 16 + bc) * LDA + kk + k8];
        acc[nt] = __builtin_amdgcn_mfma_f32_16x16x32_bf16(af, bf, acc[nt], 0, 0, 0);
      }
    }
  }
  const int trow = t0 + wave * 16 + ((lane >> 4) << 2);
#pragma unroll
  for (int nt = 0; nt < 4; nt++) {
    const int n = n0 + nt * 16 + (lane & 15);
#pragma unroll
    for (int j = 0; j < 4; j++)
      out[(size_t)(trow + j) * DHID + n] = acc[nt][j];
  }
}

// ---------------- routed down: out[tok] += h_r[e] @ wd_r[e] (K=256), atomic scatter ----------------
__global__ __launch_bounds__(256) void k_down_routed(
    const ushort* __restrict__ h_r, const ushort* __restrict__ BT,
    const int* __restrict__ cnt, const int* __restrict__ ltok,
    float* __restrict__ out)
{
  __shared__ ushort a_sh[64 * LDA], b_sh[64 * LDA];
  const int e = blockIdx.z;
  const int c = cnt[e];
  const int s0 = blockIdx.x * 64;
  if (s0 >= c) return;
  const int n0 = blockIdx.y * 64;      // over DHID=1024
  const int tid = threadIdx.x, wave = tid >> 6, lane = tid & 63;
  const int srow = tid >> 2, sseg = tid & 3;
  const ushort* Ab = h_r + (size_t)e * CAP * MR + (size_t)s0 * MR;
  const ushort* Bb = BT  + ((size_t)e * DHID + n0) * MR;

  f32x4 acc[4] = {};
  for (int k0 = 0; k0 < MR; k0 += BK) {
    __syncthreads();
    const size_t sa = (size_t)srow * MR + k0;
    *(uint4*)&a_sh[srow * LDA + sseg * 8]       = *(const uint4*)&Ab[sa + sseg * 8];
    *(uint4*)&a_sh[srow * LDA + (sseg + 4) * 8] = *(const uint4*)&Ab[sa + (sseg + 4) * 8];
    *(uint4*)&b_sh[srow * LDA + sseg * 8]       = *(const uint4*)&Bb[sa + sseg * 8];
    *(uint4*)&b_sh[srow * LDA + (sseg + 4) * 8] = *(const uint4*)&Bb[sa + (sseg + 4) * 8];
    __syncthreads();
    const int ar = wave * 16 + (lane & 15), bc = lane & 15, k8 = (lane >> 4) * 8;
#pragma unroll
    for (int kk = 0; kk < BK; kk += 32) {
      bf16x8 af = *(const bf16x8*)&a_sh[ar * LDA + kk + k8];
#pragma unroll
      for (int nt = 0; nt < 4; nt++) {
        bf16x8 bf = *(const bf16x8*)&b_sh[(nt * 16 + bc) * LDA + kk + k8];
        acc[nt] = __builtin_amdgcn_mfma_f32_16x16x32_bf16(af, bf, acc[nt], 0, 0, 0);
      }
    }
  }
  const int bc = lane & 15;
#pragma unroll
  for (int j = 0; j < 4; j++) {
    const int slot = s0 + wave * 16 + ((lane >> 4) << 2) + j;
    if (slot < c) {
      const int t = ltok[e * CAP + slot];
#pragma unroll
      for (int nt = 0; nt < 4; nt++)
        atomicAdd(&out[(size_t)t * DHID + n0 + nt * 16 + bc], acc[nt][j]);
    }
  }
}

extern "C" void kernel_launch(void* const* d_in, const int* in_sizes, int n_in,
                              void* d_out, int out_size, void* d_ws, size_t ws_size,
                              hipStream_t stream) {
  const float* x    = (const float*)d_in[0];
  const float* rw   = (const float*)d_in[1];
  const float* wg_r = (const float*)d_in[2];
  const float* wu_r = (const float*)d_in[3];
  const float* wd_r = (const float*)d_in[4];
  const float* wg_s = (const float*)d_in[5];
  const float* wu_s = (const float*)d_in[6];
  const float* wd_s = (const float*)d_in[7];
  float* out = (float*)d_out;

  char* ws = (char*)d_ws;
  size_t off = 0;
  ushort* xb   = (ushort*)(ws + off); off += (size_t)T_TOK * DHID * 2;      // 4 MB
  ushort* wgTr = (ushort*)(ws + off); off += (size_t)NEXP * MR * DHID * 2;  // 8 MB
  ushort* wuTr = (ushort*)(ws + off); off += (size_t)NEXP * MR * DHID * 2;  // 8 MB
  ushort* wdTr = (ushort*)(ws + off); off += (size_t)NEXP * DHID * MR * 2;  // 8 MB
  ushort* wgTs = (ushort*)(ws + off); off += (size_t)2 * MS * DHID * 2;     // 2 MB
  ushort* wuTs = (ushort*)(ws + off); off += (size_t)2 * MS * DHID * 2;     // 2 MB
  ushort* wdTs = (ushort*)(ws + off); off += (size_t)DHID * DHID * 2;       // 2 MB
  ushort* h_s  = (ushort*)(ws + off); off += (size_t)T_TOK * DHID * 2;      // 4 MB
  ushort* h_r  = (ushort*)(ws + off); off += (size_t)NEXP * CAP * MR * 2;   // 4 MB
  int*    cnt  = (int*)(ws + off);    off += 256;
  int*    ltok = (int*)(ws + off);    off += (size_t)NEXP * CAP * 4;
  float*  lw   = (float*)(ws + off);  off += (size_t)NEXP * CAP * 4;
  if (off > ws_size) return;  // workspace too small; bail (will show as absmax fail)

  k_zero<<<1, 64, 0, stream>>>(cnt);
  k_prep<<<T_TOK / 4, 256, 0, stream>>>(x, rw, xb, cnt, ltok, lw);

  // transposed bf16 weights: out[b][n][k]
  k_transpose<<<dim3(MR / 64, DHID / 64, NEXP), 256, 0, stream>>>(wg_r, wgTr, MR,  DHID, (size_t)MR * DHID);
  k_transpose<<<dim3(MR / 64, DHID / 64, NEXP), 256, 0, stream>>>(wu_r, wuTr, MR,  DHID, (size_t)MR * DHID);
  k_transpose<<<dim3(DHID / 64, MR / 64, NEXP), 256, 0, stream>>>(wd_r, wdTr, DHID, MR,  (size_t)DHID * MR);
  k_transpose<<<dim3(MS / 64, DHID / 64, 2),    256, 0, stream>>>(wg_s, wgTs, MS,  DHID, (size_t)MS * DHID);
  k_transpose<<<dim3(MS / 64, DHID / 64, 2),    256, 0, stream>>>(wu_s, wuTs, MS,  DHID, (size_t)MS * DHID);
  // wd_s: [2][512][1024] -> wdTs[n][e*512+m]  (out_ld=1024, batch offset=512 elements)
  k_transpose<<<dim3(DHID / 64, MS / 64, 2),    256, 0, stream>>>(wd_s, wdTs, DHID, DHID, (size_t)MS);

  k_up_shared<<<dim3(T_TOK / 64, (2 * MS) / 64), 256, 0, stream>>>(xb, wgTs, wuTs, h_s);
  k_up_routed<<<dim3(CAP / 64, MR / 64, NEXP),   256, 0, stream>>>(xb, wgTr, wuTr, cnt, ltok, lw, h_r);
  k_down_shared<<<dim3(T_TOK / 64, DHID / 64),   256, 0, stream>>>(h_s, wdTs, out);
  k_down_routed<<<dim3(CAP / 64, DHID / 64, NEXP), 256, 0, stream>>>(h_r, wdTr, cnt, ltok, out);
}

// Round 2
// 177.652 us; speedup vs baseline: 1.0586x; 1.0586x over previous
//
#include <hip/hip_runtime.h>
#include <hip/hip_bf16.h>
#include <stdint.h>

#define T_TOK 2048
#define DHID  1024
#define NEXP  16
#define MR    256
#define MS    512
#define CAP   512   // max tokens per routed expert (mean 256, std ~16)
#define BK    64
#define LDA   72    // padded LDS row stride in bf16 (bank-stride 4 -> 2-way, free)

typedef float  f32x4  __attribute__((ext_vector_type(4)));
typedef __bf16 bf16x8 __attribute__((ext_vector_type(8)));

__device__ __forceinline__ ushort f2bf(float f) {
  uint32_t u = __float_as_uint(f);
  u = (u + 0x7fffu + ((u >> 16) & 1u)) >> 16;
  return (ushort)u;
}

// ---------------- zero the per-expert counters ----------------
__global__ void k_zero(int* c) {
  if (threadIdx.x < NEXP) c[threadIdx.x] = 0;
}

// ---------------- convert x to bf16 + fp32 router + expert lists ----------------
// rw staged in LDS transposed [e][d]: lane-stride-1 reads -> conflict-free.
__global__ __launch_bounds__(256) void k_prep(
    const float* __restrict__ x, const float* __restrict__ rw,
    ushort* __restrict__ xb, int* __restrict__ cnt,
    int* __restrict__ ltok, float* __restrict__ lw)
{
  __shared__ float rw_sh[NEXP][DHID];   // 64 KB, exactly sharedMemPerBlock
  const int tid = threadIdx.x;
  // stage rw transposed: global [d][e] -> lds [e][d]
#pragma unroll
  for (int it = 0; it < 16; ++it) {
    const int flat = it * 1024 + tid * 4;     // 16384 elems total
    float4 v = *(const float4*)&rw[flat];
    const int d = flat >> 4, e = flat & 15;   // e, e+1, e+2, e+3 same d
    rw_sh[e + 0][d] = v.x; rw_sh[e + 1][d] = v.y;
    rw_sh[e + 2][d] = v.z; rw_sh[e + 3][d] = v.w;
  }
  __syncthreads();

  const int wave = tid >> 6, lane = tid & 63;
  const int t = blockIdx.x * 4 + wave;        // 1 token per wave
  const float* xp = x + (size_t)t * DHID;

  float acc[NEXP];
#pragma unroll
  for (int e = 0; e < NEXP; e++) acc[e] = 0.f;

#pragma unroll
  for (int i = 0; i < 16; ++i) {
    const int d = i * 64 + lane;              // lane-stride 1: coalesced x, CF lds
    const float xv = xp[d];
    xb[(size_t)t * DHID + d] = f2bf(xv);
#pragma unroll
    for (int e = 0; e < NEXP; e++) acc[e] = fmaf(xv, rw_sh[e][d], acc[e]);
  }

  // wave butterfly reduce (all lanes end with totals)
#pragma unroll
  for (int off = 32; off >= 1; off >>= 1) {
#pragma unroll
    for (int e = 0; e < NEXP; e++) acc[e] += __shfl_xor(acc[e], off, 64);
  }
  if (lane == 0) {
    float m = acc[0];
#pragma unroll
    for (int e = 1; e < NEXP; e++) m = fmaxf(m, acc[e]);
    float p[NEXP], Z = 0.f;
#pragma unroll
    for (int e = 0; e < NEXP; e++) { p[e] = __expf(acc[e] - m); Z += p[e]; }
    const float inv = 1.f / Z;
    int i1 = 0; float p1 = p[0] * inv;
    for (int e = 1; e < NEXP; e++) { float pe = p[e] * inv; if (pe > p1) { p1 = pe; i1 = e; } }
    int i2 = -1; float p2 = -1.f;
    for (int e = 0; e < NEXP; e++) { if (e == i1) continue; float pe = p[e] * inv; if (pe > p2) { p2 = pe; i2 = e; } }
    const float denom = p1 + p2 + 1e-9f;
    const float w1 = p1 / denom, w2 = p2 / denom;
    int pos1 = atomicAdd(&cnt[i1], 1);
    if (pos1 < CAP) { ltok[i1 * CAP + pos1] = t; lw[i1 * CAP + pos1] = w1; }
    int pos2 = atomicAdd(&cnt[i2], 1);
    if (pos2 < CAP) { ltok[i2 * CAP + pos2] = t; lw[i2 * CAP + pos2] = w2; }
  }
}

// ---------------- transpose+convert weights: in [B][R][C] f32 -> out[b][c][r] bf16 ----------------
// out element index: b*out_batch + c*out_ld + r
__global__ __launch_bounds__(256) void k_transpose(
    const float* __restrict__ in, ushort* __restrict__ out,
    int C, int out_ld, size_t out_batch)
{
  __shared__ float t_sh[64][65];
  const int b = blockIdx.z;
  const int r0 = blockIdx.y * 64, c0 = blockIdx.x * 64;
  const float* ip = in + (size_t)b * (size_t)gridDim.y * 64 * C;
  const int tr = threadIdx.x >> 4;          // 0..15
  const int tc = (threadIdx.x & 15) * 4;    // 0..60
#pragma unroll
  for (int p = 0; p < 4; p++) {
    float4 v = *(const float4*)&ip[(size_t)(r0 + tr + p * 16) * C + c0 + tc];
    t_sh[tr + p * 16][tc + 0] = v.x; t_sh[tr + p * 16][tc + 1] = v.y;
    t_sh[tr + p * 16][tc + 2] = v.z; t_sh[tr + p * 16][tc + 3] = v.w;
  }
  __syncthreads();
  ushort* op = out + (size_t)b * out_batch;
#pragma unroll
  for (int p = 0; p < 4; p++) {
    const int cc = tr + p * 16;
    ushort4 o;
    o.x = f2bf(t_sh[tc + 0][cc]); o.y = f2bf(t_sh[tc + 1][cc]);
    o.z = f2bf(t_sh[tc + 2][cc]); o.w = f2bf(t_sh[tc + 3][cc]);
    *(ushort4*)&op[(size_t)(c0 + cc) * out_ld + r0 + tc] = o;
  }
}

// ---------------- shared experts: G=X@Wg, U=X@Wu, h = silu(G)*U -> h_s[t][e*512+m] ----------------
__global__ __launch_bounds__(256) void k_up_shared(
    const ushort* __restrict__ xb, const ushort* __restrict__ wgT,
    const ushort* __restrict__ wuT, ushort* __restrict__ h_s)
{
  __shared__ ushort a_sh[64 * LDA], g_sh[64 * LDA], u_sh[64 * LDA];
  const int t0 = blockIdx.x * 64;
  const int gn0 = blockIdx.y * 64;      // over 2*MS = 1024 (e*512+m)
  const int tid = threadIdx.x, wave = tid >> 6, lane = tid & 63;
  const int srow = tid >> 2, sseg = tid & 3;

  const ushort* Ab = xb  + (size_t)t0  * DHID;
  const ushort* Gb = wgT + (size_t)gn0 * DHID;
  const ushort* Ub = wuT + (size_t)gn0 * DHID;

  f32x4 accg[4] = {}; f32x4 accu[4] = {};
  for (int k0 = 0; k0 < DHID; k0 += BK) {
    __syncthreads();
    const size_t so = (size_t)srow * DHID + k0;
    *(uint4*)&a_sh[srow * LDA + sseg * 8]       = *(const uint4*)&Ab[so + sseg * 8];
    *(uint4*)&a_sh[srow * LDA + (sseg + 4) * 8] = *(const uint4*)&Ab[so + (sseg + 4) * 8];
    *(uint4*)&g_sh[srow * LDA + sseg * 8]       = *(const uint4*)&Gb[so + sseg * 8];
    *(uint4*)&g_sh[srow * LDA + (sseg + 4) * 8] = *(const uint4*)&Gb[so + (sseg + 4) * 8];
    *(uint4*)&u_sh[srow * LDA + sseg * 8]       = *(const uint4*)&Ub[so + sseg * 8];
    *(uint4*)&u_sh[srow * LDA + (sseg + 4) * 8] = *(const uint4*)&Ub[so + (sseg + 4) * 8];
    __syncthreads();
    const int ar = wave * 16 + (lane & 15), bc = lane & 15, k8 = (lane >> 4) * 8;
#pragma unroll
    for (int kk = 0; kk < BK; kk += 32) {
      bf16x8 af = *(const bf16x8*)&a_sh[ar * LDA + kk + k8];
#pragma unroll
      for (int nt = 0; nt < 4; nt++) {
        bf16x8 gf = *(const bf16x8*)&g_sh[(nt * 16 + bc) * LDA + kk + k8];
        bf16x8 uf = *(const bf16x8*)&u_sh[(nt * 16 + bc) * LDA + kk + k8];
        accg[nt] = __builtin_amdgcn_mfma_f32_16x16x32_bf16(af, gf, accg[nt], 0, 0, 0);
        accu[nt] = __builtin_amdgcn_mfma_f32_16x16x32_bf16(af, uf, accu[nt], 0, 0, 0);
      }
    }
  }
  const int trow = t0 + wave * 16 + ((lane >> 4) << 2);
#pragma unroll
  for (int nt = 0; nt < 4; nt++) {
    const int n = gn0 + nt * 16 + (lane & 15);
#pragma unroll
    for (int j = 0; j < 4; j++) {
      float g = accg[nt][j], u = accu[nt][j];
      float h = (g / (1.f + __expf(-g))) * u;
      h_s[(size_t)(trow + j) * DHID + n] = f2bf(h);
    }
  }
}

// ---------------- routed experts up: gathered rows, h = silu(g)*u*w -> h_r[e][slot][m] ----------------
__global__ __launch_bounds__(256) void k_up_routed(
    const ushort* __restrict__ xb, const ushort* __restrict__ wgT,
    const ushort* __restrict__ wuT, const int* __restrict__ cnt,
    const int* __restrict__ ltok, const float* __restrict__ lw,
    ushort* __restrict__ h_r)
{
  __shared__ ushort a_sh[64 * LDA], g_sh[64 * LDA], u_sh[64 * LDA];
  const int e = blockIdx.z;
  const int c = cnt[e];
  const int s0 = blockIdx.x * 64;
  if (s0 >= c) return;
  const int m0 = blockIdx.y * 64;       // over MR=256
  const int tid = threadIdx.x, wave = tid >> 6, lane = tid & 63;
  const int srow = tid >> 2, sseg = tid & 3;

  const int stok = (s0 + srow < c) ? ltok[e * CAP + s0 + srow] : -1;
  const ushort* Gb = wgT + ((size_t)e * MR + m0) * DHID;
  const ushort* Ub = wuT + ((size_t)e * MR + m0) * DHID;

  f32x4 accg[4] = {}; f32x4 accu[4] = {};
  for (int k0 = 0; k0 < DHID; k0 += BK) {
    __syncthreads();
    uint4 av0 = {0, 0, 0, 0}, av1 = {0, 0, 0, 0};
    if (stok >= 0) {
      const size_t xo = (size_t)stok * DHID + k0;
      av0 = *(const uint4*)&xb[xo + sseg * 8];
      av1 = *(const uint4*)&xb[xo + (sseg + 4) * 8];
    }
    *(uint4*)&a_sh[srow * LDA + sseg * 8]       = av0;
    *(uint4*)&a_sh[srow * LDA + (sseg + 4) * 8] = av1;
    const size_t so = (size_t)srow * DHID + k0;
    *(uint4*)&g_sh[srow * LDA + sseg * 8]       = *(const uint4*)&Gb[so + sseg * 8];
    *(uint4*)&g_sh[srow * LDA + (sseg + 4) * 8] = *(const uint4*)&Gb[so + (sseg + 4) * 8];
    *(uint4*)&u_sh[srow * LDA + sseg * 8]       = *(const uint4*)&Ub[so + sseg * 8];
    *(uint4*)&u_sh[srow * LDA + (sseg + 4) * 8] = *(const uint4*)&Ub[so + (sseg + 4) * 8];
    __syncthreads();
    const int ar = wave * 16 + (lane & 15), bc = lane & 15, k8 = (lane >> 4) * 8;
#pragma unroll
    for (int kk = 0; kk < BK; kk += 32) {
      bf16x8 af = *(const bf16x8*)&a_sh[ar * LDA + kk + k8];
#pragma unroll
      for (int nt = 0; nt < 4; nt++) {
        bf16x8 gf = *(const bf16x8*)&g_sh[(nt * 16 + bc) * LDA + kk + k8];
        bf16x8 uf = *(const bf16x8*)&u_sh[(nt * 16 + bc) * LDA + kk + k8];
        accg[nt] = __builtin_amdgcn_mfma_f32_16x16x32_bf16(af, gf, accg[nt], 0, 0, 0);
        accu[nt] = __builtin_amdgcn_mfma_f32_16x16x32_bf16(af, uf, accu[nt], 0, 0, 0);
      }
    }
  }
  const int bc = lane & 15;
#pragma unroll
  for (int j = 0; j < 4; j++) {
    const int slot = s0 + wave * 16 + ((lane >> 4) << 2) + j;
    if (slot < c) {
      const float w = lw[e * CAP + slot];
#pragma unroll
      for (int nt = 0; nt < 4; nt++) {
        float g = accg[nt][j], u = accu[nt][j];
        float h = (g / (1.f + __expf(-g))) * u * w;
        h_r[(size_t)e * CAP * MR + (size_t)slot * MR + m0 + nt * 16 + bc] = f2bf(h);
      }
    }
  }
}

// ---------------- shared down: out = h_s @ wd_cat (K=1024), plain stores ----------------
__global__ __launch_bounds__(256) void k_down_shared(
    const ushort* __restrict__ A, const ushort* __restrict__ BT,
    float* __restrict__ out)
{
  __shared__ ushort a_sh[64 * LDA], b_sh[64 * LDA];
  const int t0 = blockIdx.x * 64, n0 = blockIdx.y * 64;
  const int tid = threadIdx.x, wave = tid >> 6, lane = tid & 63;
  const int srow = tid >> 2, sseg = tid & 3;
  const ushort* Ab = A  + (size_t)t0 * DHID;
  const ushort* Bb = BT + (size_t)n0 * DHID;

  f32x4 acc[4] = {};
  for (int k0 = 0; k0 < DHID; k0 += BK) {
    __syncthreads();
    const size_t so = (size_t)srow * DHID + k0;
    *(uint4*)&a_sh[srow * LDA + sseg * 8]       = *(const uint4*)&Ab[so + sseg * 8];
    *(uint4*)&a_sh[srow * LDA + (sseg + 4) * 8] = *(const uint4*)&Ab[so + (sseg + 4) * 8];
    *(uint4*)&b_sh[srow * LDA + sseg * 8]       = *(const uint4*)&Bb[so + sseg * 8];
    *(uint4*)&b_sh[srow * LDA + (sseg + 4) * 8] = *(const uint4*)&Bb[so + (sseg + 4) * 8];
    __syncthreads();
    const int ar = wave * 16 + (lane & 15), bc = lane & 15, k8 = (lane >> 4) * 8;
#pragma unroll
    for (int kk = 0; kk < BK; kk += 32) {
      bf16x8 af = *(const bf16x8*)&a_sh[ar * LDA + kk + k8];
#pragma unroll
      for (int nt = 0; nt < 4; nt++) {
        bf16x8 bf = *(const bf16x8*)&b_sh[(nt * 16 + bc) * LDA + kk + k8];
        acc[nt] = __builtin_amdgcn_mfma_f32_16x16x32_bf16(af, bf, acc[nt], 0, 0, 0);
      }
    }
  }
  const int trow = t0 + wave * 16 + ((lane >> 4) << 2);
#pragma unroll
  for (int nt = 0; nt < 4; nt++) {
    const int n = n0 + nt * 16 + (lane & 15);
#pragma unroll
    for (int j = 0; j < 4; j++)
      out[(size_t)(trow + j) * DHID + n] = acc[nt][j];
  }
}

// ---------------- routed down: out[tok] += h_r[e] @ wd_r[e] (K=256), atomic scatter ----------------
__global__ __launch_bounds__(256) void k_down_routed(
    const ushort* __restrict__ h_r, const ushort* __restrict__ BT,
    const int* __restrict__ cnt, const int* __restrict__ ltok,
    float* __restrict__ out)
{
  __shared__ ushort a_sh[64 * LDA], b_sh[64 * LDA];
  const int e = blockIdx.z;
  const int c = cnt[e];
  const int s0 = blockIdx.x * 64;
  if (s0 >= c) return;
  const int n0 = blockIdx.y * 64;      // over DHID=1024
  const int tid = threadIdx.x, wave = tid >> 6, lane = tid & 63;
  const int srow = tid >> 2, sseg = tid & 3;
  const ushort* Ab = h_r + (size_t)e * CAP * MR + (size_t)s0 * MR;
  const ushort* Bb = BT  + ((size_t)e * DHID + n0) * MR;

  f32x4 acc[4] = {};
  for (int k0 = 0; k0 < MR; k0 += BK) {
    __syncthreads();
    const size_t sa = (size_t)srow * MR + k0;
    *(uint4*)&a_sh[srow * LDA + sseg * 8]       = *(const uint4*)&Ab[sa + sseg * 8];
    *(uint4*)&a_sh[srow * LDA + (sseg + 4) * 8] = *(const uint4*)&Ab[sa + (sseg + 4) * 8];
    *(uint4*)&b_sh[srow * LDA + sseg * 8]       = *(const uint4*)&Bb[sa + sseg * 8];
    *(uint4*)&b_sh[srow * LDA + (sseg + 4) * 8] = *(const uint4*)&Bb[sa + (sseg + 4) * 8];
    __syncthreads();
    const int ar = wave * 16 + (lane & 15), bc = lane & 15, k8 = (lane >> 4) * 8;
#pragma unroll
    for (int kk = 0; kk < BK; kk += 32) {
      bf16x8 af = *(const bf16x8*)&a_sh[ar * LDA + kk + k8];
#pragma unroll
      for (int nt = 0; nt < 4; nt++) {
        bf16x8 bf = *(const bf16x8*)&b_sh[(nt * 16 + bc) * LDA + kk + k8];
        acc[nt] = __builtin_amdgcn_mfma_f32_16x16x32_bf16(af, bf, acc[nt], 0, 0, 0);
      }
    }
  }
  const int bc = lane & 15;
#pragma unroll
  for (int j = 0; j < 4; j++) {
    const int slot = s0 + wave * 16 + ((lane >> 4) << 2) + j;
    if (slot < c) {
      const int t = ltok[e * CAP + slot];
#pragma unroll
      for (int nt = 0; nt < 4; nt++)
        atomicAdd(&out[(size_t)t * DHID + n0 + nt * 16 + bc], acc[nt][j]);
    }
  }
}

extern "C" void kernel_launch(void* const* d_in, const int* in_sizes, int n_in,
                              void* d_out, int out_size, void* d_ws, size_t ws_size,
                              hipStream_t stream) {
  const float* x    = (const float*)d_in[0];
  const float* rw   = (const float*)d_in[1];
  const float* wg_r = (const float*)d_in[2];
  const float* wu_r = (const float*)d_in[3];
  const float* wd_r = (const float*)d_in[4];
  const float* wg_s = (const float*)d_in[5];
  const float* wu_s = (const float*)d_in[6];
  const float* wd_s = (const float*)d_in[7];
  float* out = (float*)d_out;

  char* ws = (char*)d_ws;
  size_t off = 0;
  ushort* xb   = (ushort*)(ws + off); off += (size_t)T_TOK * DHID * 2;      // 4 MB
  ushort* wgTr = (ushort*)(ws + off); off += (size_t)NEXP * MR * DHID * 2;  // 8 MB
  ushort* wuTr = (ushort*)(ws + off); off += (size_t)NEXP * MR * DHID * 2;  // 8 MB
  ushort* wdTr = (ushort*)(ws + off); off += (size_t)NEXP * DHID * MR * 2;  // 8 MB
  ushort* wgTs = (ushort*)(ws + off); off += (size_t)2 * MS * DHID * 2;     // 2 MB
  ushort* wuTs = (ushort*)(ws + off); off += (size_t)2 * MS * DHID * 2;     // 2 MB
  ushort* wdTs = (ushort*)(ws + off); off += (size_t)DHID * DHID * 2;       // 2 MB
  ushort* h_s  = (ushort*)(ws + off); off += (size_t)T_TOK * DHID * 2;      // 4 MB
  ushort* h_r  = (ushort*)(ws + off); off += (size_t)NEXP * CAP * MR * 2;   // 4 MB
  int*    cnt  = (int*)(ws + off);    off += 256;
  int*    ltok = (int*)(ws + off);    off += (size_t)NEXP * CAP * 4;
  float*  lw   = (float*)(ws + off);  off += (size_t)NEXP * CAP * 4;
  if (off > ws_size) return;  // workspace too small; bail (will show as absmax fail)

  k_zero<<<1, 64, 0, stream>>>(cnt);
  k_prep<<<T_TOK / 4, 256, 0, stream>>>(x, rw, xb, cnt, ltok, lw);

  // transposed bf16 weights: out[b][n][k]
  k_transpose<<<dim3(MR / 64, DHID / 64, NEXP), 256, 0, stream>>>(wg_r, wgTr, MR,  DHID, (size_t)MR * DHID);
  k_transpose<<<dim3(MR / 64, DHID / 64, NEXP), 256, 0, stream>>>(wu_r, wuTr, MR,  DHID, (size_t)MR * DHID);
  k_transpose<<<dim3(DHID / 64, MR / 64, NEXP), 256, 0, stream>>>(wd_r, wdTr, DHID, MR,  (size_t)DHID * MR);
  k_transpose<<<dim3(MS / 64, DHID / 64, 2),    256, 0, stream>>>(wg_s, wgTs, MS,  DHID, (size_t)MS * DHID);
  k_transpose<<<dim3(MS / 64, DHID / 64, 2),    256, 0, stream>>>(wu_s, wuTs, MS,  DHID, (size_t)MS * DHID);
  // wd_s: [2][512][1024] -> wdTs[n][e*512+m]  (out_ld=1024, batch offset=512 elements)
  k_transpose<<<dim3(DHID / 64, MS / 64, 2),    256, 0, stream>>>(wd_s, wdTs, DHID, DHID, (size_t)MS);

  k_up_shared<<<dim3(T_TOK / 64, (2 * MS) / 64), 256, 0, stream>>>(xb, wgTs, wuTs, h_s);
  k_up_routed<<<dim3(CAP / 64, MR / 64, NEXP),   256, 0, stream>>>(xb, wgTr, wuTr, cnt, ltok, lw, h_r);
  k_down_shared<<<dim3(T_TOK / 64, DHID / 64),   256, 0, stream>>>(h_s, wdTs, out);
  k_down_routed<<<dim3(CAP / 64, DHID / 64, NEXP), 256, 0, stream>>>(h_r, wdTr, cnt, ltok, out);
}

// Round 3
// 132.585 us; speedup vs baseline: 1.4185x; 1.3399x over previous
//
#include <hip/hip_runtime.h>
#include <hip/hip_bf16.h>
#include <stdint.h>

#define T_TOK 2048
#define DHID  1024
#define NEXP  16
#define MR    256
#define MS    512
#define CAP   512   // max tokens per routed expert (mean 256)
#define BK    64
#define LDA   72    // padded LDS row stride in bf16 (bank-stride 4 -> 2-way, free)

typedef float  f32x4  __attribute__((ext_vector_type(4)));
typedef __bf16 bf16x8 __attribute__((ext_vector_type(8)));

__device__ __forceinline__ ushort f2bf(float f) {
  uint32_t u = __float_as_uint(f);
  u = (u + 0x7fffu + ((u >> 16) & 1u)) >> 16;
  return (ushort)u;
}

// ---------------- x->bf16 + fp32 router; dense per-token top2 output (NO atomics) ----------------
__global__ __launch_bounds__(256) void k_prep(
    const float* __restrict__ x, const float* __restrict__ rw,
    ushort* __restrict__ xb, int* __restrict__ topi, float2* __restrict__ topw)
{
  __shared__ float rw_sh[NEXP][DHID];   // 64 KB, transposed [e][d]
  const int tid = threadIdx.x;
#pragma unroll
  for (int it = 0; it < 16; ++it) {
    const int flat = it * 1024 + tid * 4;     // 16384 elems total
    float4 v = *(const float4*)&rw[flat];
    const int d = flat >> 4, e = flat & 15;
    rw_sh[e + 0][d] = v.x; rw_sh[e + 1][d] = v.y;
    rw_sh[e + 2][d] = v.z; rw_sh[e + 3][d] = v.w;
  }
  __syncthreads();

  const int wave = tid >> 6, lane = tid & 63;
  const int t = blockIdx.x * 4 + wave;        // 1 token per wave
  const float* xp = x + (size_t)t * DHID;

  float acc[NEXP];
#pragma unroll
  for (int e = 0; e < NEXP; e++) acc[e] = 0.f;

#pragma unroll
  for (int i = 0; i < 4; ++i) {
    const int d4 = i * 64 + lane;             // float4 row index, lane-consecutive
    float4 xv = *(const float4*)&xp[d4 * 4];
    ushort4 o; o.x = f2bf(xv.x); o.y = f2bf(xv.y); o.z = f2bf(xv.z); o.w = f2bf(xv.w);
    *(ushort4*)&xb[(size_t)t * DHID + d4 * 4] = o;
#pragma unroll
    for (int e = 0; e < NEXP; e++) {
      float4 wv = *(const float4*)&rw_sh[e][d4 * 4];   // ds_read_b128, conflict-free
      acc[e] = fmaf(xv.x, wv.x, acc[e]);
      acc[e] = fmaf(xv.y, wv.y, acc[e]);
      acc[e] = fmaf(xv.z, wv.z, acc[e]);
      acc[e] = fmaf(xv.w, wv.w, acc[e]);
    }
  }

  // wave butterfly reduce
#pragma unroll
  for (int off = 32; off >= 1; off >>= 1) {
#pragma unroll
    for (int e = 0; e < NEXP; e++) acc[e] += __shfl_xor(acc[e], off, 64);
  }
  if (lane == 0) {
    float m = acc[0];
#pragma unroll
    for (int e = 1; e < NEXP; e++) m = fmaxf(m, acc[e]);
    float p[NEXP], Z = 0.f;
#pragma unroll
    for (int e = 0; e < NEXP; e++) { p[e] = __expf(acc[e] - m); Z += p[e]; }
    const float inv = 1.f / Z;
    int i1 = 0; float p1 = p[0] * inv;
    for (int e = 1; e < NEXP; e++) { float pe = p[e] * inv; if (pe > p1) { p1 = pe; i1 = e; } }
    int i2 = -1; float p2 = -1.f;
    for (int e = 0; e < NEXP; e++) { if (e == i1) continue; float pe = p[e] * inv; if (pe > p2) { p2 = pe; i2 = e; } }
    const float denom = p1 + p2 + 1e-9f;
    topi[t] = i1 | (i2 << 8);
    topw[t] = make_float2(p1 / denom, p2 / denom);
  }
}

// ---------------- build per-expert compacted token lists (deterministic, no atomics) ----------------
__global__ __launch_bounds__(256) void k_build(
    const int* __restrict__ topi, const float2* __restrict__ topw,
    int* __restrict__ cnt, int* __restrict__ ltok, float* __restrict__ lw)
{
  __shared__ int wsum[4];
  const int e = blockIdx.x;
  const int tid = threadIdx.x, wave = tid >> 6, lane = tid & 63;
  const int t0 = tid * 8;                      // 8 tokens per thread

  int4 a = *(const int4*)&topi[t0];
  int4 b = *(const int4*)&topi[t0 + 4];
  int ti[8] = {a.x, a.y, a.z, a.w, b.x, b.y, b.z, b.w};
  int match[8]; int c = 0;
#pragma unroll
  for (int k = 0; k < 8; ++k) {
    const int i1 = ti[k] & 0xff, i2 = (ti[k] >> 8) & 0xff;
    match[k] = (i1 == e) ? 1 : ((i2 == e) ? 2 : 0);
    c += (match[k] != 0);
  }
  int incl = c;
#pragma unroll
  for (int off = 1; off < 64; off <<= 1) {
    int n = __shfl_up(incl, off, 64);
    if (lane >= off) incl += n;
  }
  if (lane == 63) wsum[wave] = incl;
  __syncthreads();
  int base = incl - c;                         // exclusive within wave
  for (int w = 0; w < wave; ++w) base += wsum[w];
  if (tid == 0) {
    int tot = wsum[0] + wsum[1] + wsum[2] + wsum[3];
    cnt[e] = tot > CAP ? CAP : tot;
  }
#pragma unroll
  for (int k = 0; k < 8; ++k) {
    if (match[k]) {
      if (base < CAP) {
        float2 w2 = topw[t0 + k];
        ltok[e * CAP + base] = t0 + k;
        lw[e * CAP + base] = (match[k] == 1) ? w2.x : w2.y;
      }
      base++;
    }
  }
}

// ---------------- transpose+convert weights: in [B][R][C] f32 -> out[b][c][r] bf16 ----------------
__global__ __launch_bounds__(256) void k_transpose(
    const float* __restrict__ in, ushort* __restrict__ out,
    int C, int out_ld, size_t out_batch)
{
  __shared__ float t_sh[64][65];
  const int b = blockIdx.z;
  const int r0 = blockIdx.y * 64, c0 = blockIdx.x * 64;
  const float* ip = in + (size_t)b * (size_t)gridDim.y * 64 * C;
  const int tr = threadIdx.x >> 4;          // 0..15
  const int tc = (threadIdx.x & 15) * 4;    // 0..60
#pragma unroll
  for (int p = 0; p < 4; p++) {
    float4 v = *(const float4*)&ip[(size_t)(r0 + tr + p * 16) * C + c0 + tc];
    t_sh[tr + p * 16][tc + 0] = v.x; t_sh[tr + p * 16][tc + 1] = v.y;
    t_sh[tr + p * 16][tc + 2] = v.z; t_sh[tr + p * 16][tc + 3] = v.w;
  }
  __syncthreads();
  ushort* op = out + (size_t)b * out_batch;
#pragma unroll
  for (int p = 0; p < 4; p++) {
    const int cc = tr + p * 16;
    ushort4 o;
    o.x = f2bf(t_sh[tc + 0][cc]); o.y = f2bf(t_sh[tc + 1][cc]);
    o.z = f2bf(t_sh[tc + 2][cc]); o.w = f2bf(t_sh[tc + 3][cc]);
    *(ushort4*)&op[(size_t)(c0 + cc) * out_ld + r0 + tc] = o;
  }
}

// ---------------- shared experts: G=X@Wg, U=X@Wu, h = silu(G)*U -> h_s[t][e*512+m] ----------------
__global__ __launch_bounds__(256) void k_up_shared(
    const ushort* __restrict__ xb, const ushort* __restrict__ wgT,
    const ushort* __restrict__ wuT, ushort* __restrict__ h_s)
{
  __shared__ ushort a_sh[64 * LDA], g_sh[64 * LDA], u_sh[64 * LDA];
  const int t0 = blockIdx.x * 64;
  const int gn0 = blockIdx.y * 64;      // over 2*MS = 1024 (e*512+m)
  const int tid = threadIdx.x, wave = tid >> 6, lane = tid & 63;
  const int srow = tid >> 2, sseg = tid & 3;

  const ushort* Ab = xb  + (size_t)t0  * DHID;
  const ushort* Gb = wgT + (size_t)gn0 * DHID;
  const ushort* Ub = wuT + (size_t)gn0 * DHID;

  f32x4 accg[4] = {}; f32x4 accu[4] = {};
  for (int k0 = 0; k0 < DHID; k0 += BK) {
    __syncthreads();
    const size_t so = (size_t)srow * DHID + k0;
    *(uint4*)&a_sh[srow * LDA + sseg * 8]       = *(const uint4*)&Ab[so + sseg * 8];
    *(uint4*)&a_sh[srow * LDA + (sseg + 4) * 8] = *(const uint4*)&Ab[so + (sseg + 4) * 8];
    *(uint4*)&g_sh[srow * LDA + sseg * 8]       = *(const uint4*)&Gb[so + sseg * 8];
    *(uint4*)&g_sh[srow * LDA + (sseg + 4) * 8] = *(const uint4*)&Gb[so + (sseg + 4) * 8];
    *(uint4*)&u_sh[srow * LDA + sseg * 8]       = *(const uint4*)&Ub[so + sseg * 8];
    *(uint4*)&u_sh[srow * LDA + (sseg + 4) * 8] = *(const uint4*)&Ub[so + (sseg + 4) * 8];
    __syncthreads();
    const int ar = wave * 16 + (lane & 15), bc = lane & 15, k8 = (lane >> 4) * 8;
#pragma unroll
    for (int kk = 0; kk < BK; kk += 32) {
      bf16x8 af = *(const bf16x8*)&a_sh[ar * LDA + kk + k8];
#pragma unroll
      for (int nt = 0; nt < 4; nt++) {
        bf16x8 gf = *(const bf16x8*)&g_sh[(nt * 16 + bc) * LDA + kk + k8];
        bf16x8 uf = *(const bf16x8*)&u_sh[(nt * 16 + bc) * LDA + kk + k8];
        accg[nt] = __builtin_amdgcn_mfma_f32_16x16x32_bf16(af, gf, accg[nt], 0, 0, 0);
        accu[nt] = __builtin_amdgcn_mfma_f32_16x16x32_bf16(af, uf, accu[nt], 0, 0, 0);
      }
    }
  }
  const int trow = t0 + wave * 16 + ((lane >> 4) << 2);
#pragma unroll
  for (int nt = 0; nt < 4; nt++) {
    const int n = gn0 + nt * 16 + (lane & 15);
#pragma unroll
    for (int j = 0; j < 4; j++) {
      float g = accg[nt][j], u = accu[nt][j];
      float h = (g / (1.f + __expf(-g))) * u;
      h_s[(size_t)(trow + j) * DHID + n] = f2bf(h);
    }
  }
}

// ---------------- routed experts up: gathered rows, h = silu(g)*u*w -> h_r[e][slot][m] ----------------
__global__ __launch_bounds__(256) void k_up_routed(
    const ushort* __restrict__ xb, const ushort* __restrict__ wgT,
    const ushort* __restrict__ wuT, const int* __restrict__ cnt,
    const int* __restrict__ ltok, const float* __restrict__ lw,
    ushort* __restrict__ h_r)
{
  __shared__ ushort a_sh[64 * LDA], g_sh[64 * LDA], u_sh[64 * LDA];
  const int e = blockIdx.z;
  const int c = cnt[e];
  const int s0 = blockIdx.x * 64;
  if (s0 >= c) return;
  const int m0 = blockIdx.y * 64;       // over MR=256
  const int tid = threadIdx.x, wave = tid >> 6, lane = tid & 63;
  const int srow = tid >> 2, sseg = tid & 3;

  const int stok = (s0 + srow < c) ? ltok[e * CAP + s0 + srow] : -1;
  const ushort* Gb = wgT + ((size_t)e * MR + m0) * DHID;
  const ushort* Ub = wuT + ((size_t)e * MR + m0) * DHID;

  f32x4 accg[4] = {}; f32x4 accu[4] = {};
  for (int k0 = 0; k0 < DHID; k0 += BK) {
    __syncthreads();
    uint4 av0 = {0, 0, 0, 0}, av1 = {0, 0, 0, 0};
    if (stok >= 0) {
      const size_t xo = (size_t)stok * DHID + k0;
      av0 = *(const uint4*)&xb[xo + sseg * 8];
      av1 = *(const uint4*)&xb[xo + (sseg + 4) * 8];
    }
    *(uint4*)&a_sh[srow * LDA + sseg * 8]       = av0;
    *(uint4*)&a_sh[srow * LDA + (sseg + 4) * 8] = av1;
    const size_t so = (size_t)srow * DHID + k0;
    *(uint4*)&g_sh[srow * LDA + sseg * 8]       = *(const uint4*)&Gb[so + sseg * 8];
    *(uint4*)&g_sh[srow * LDA + (sseg + 4) * 8] = *(const uint4*)&Gb[so + (sseg + 4) * 8];
    *(uint4*)&u_sh[srow * LDA + sseg * 8]       = *(const uint4*)&Ub[so + sseg * 8];
    *(uint4*)&u_sh[srow * LDA + (sseg + 4) * 8] = *(const uint4*)&Ub[so + (sseg + 4) * 8];
    __syncthreads();
    const int ar = wave * 16 + (lane & 15), bc = lane & 15, k8 = (lane >> 4) * 8;
#pragma unroll
    for (int kk = 0; kk < BK; kk += 32) {
      bf16x8 af = *(const bf16x8*)&a_sh[ar * LDA + kk + k8];
#pragma unroll
      for (int nt = 0; nt < 4; nt++) {
        bf16x8 gf = *(const bf16x8*)&g_sh[(nt * 16 + bc) * LDA + kk + k8];
        bf16x8 uf = *(const bf16x8*)&u_sh[(nt * 16 + bc) * LDA + kk + k8];
        accg[nt] = __builtin_amdgcn_mfma_f32_16x16x32_bf16(af, gf, accg[nt], 0, 0, 0);
        accu[nt] = __builtin_amdgcn_mfma_f32_16x16x32_bf16(af, uf, accu[nt], 0, 0, 0);
      }
    }
  }
  const int bc = lane & 15;
#pragma unroll
  for (int j = 0; j < 4; j++) {
    const int slot = s0 + wave * 16 + ((lane >> 4) << 2) + j;
    if (slot < c) {
      const float w = lw[e * CAP + slot];
#pragma unroll
      for (int nt = 0; nt < 4; nt++) {
        float g = accg[nt][j], u = accu[nt][j];
        float h = (g / (1.f + __expf(-g))) * u * w;
        h_r[(size_t)e * CAP * MR + (size_t)slot * MR + m0 + nt * 16 + bc] = f2bf(h);
      }
    }
  }
}

// ---------------- shared down: out = h_s @ wd_cat (K=1024), plain stores ----------------
__global__ __launch_bounds__(256) void k_down_shared(
    const ushort* __restrict__ A, const ushort* __restrict__ BT,
    float* __restrict__ out)
{
  __shared__ ushort a_sh[64 * LDA], b_sh[64 * LDA];
  const int t0 = blockIdx.x * 64, n0 = blockIdx.y * 64;
  const int tid = threadIdx.x, wave = tid >> 6, lane = tid & 63;
  const int srow = tid >> 2, sseg = tid & 3;
  const ushort* Ab = A  + (size_t)t0 * DHID;
  const ushort* Bb = BT + (size_t)n0 * DHID;

  f32x4 acc[4] = {};
  for (int k0 = 0; k0 < DHID; k0 += BK) {
    __syncthreads();
    const size_t so = (size_t)srow * DHID + k0;
    *(uint4*)&a_sh[srow * LDA + sseg * 8]       = *(const uint4*)&Ab[so + sseg * 8];
    *(uint4*)&a_sh[srow * LDA + (sseg + 4) * 8] = *(const uint4*)&Ab[so + (sseg + 4) * 8];
    *(uint4*)&b_sh[srow * LDA + sseg * 8]       = *(const uint4*)&Bb[so + sseg * 8];
    *(uint4*)&b_sh[srow * LDA + (sseg + 4) * 8] = *(const uint4*)&Bb[so + (sseg + 4) * 8];
    __syncthreads();
    const int ar = wave * 16 + (lane & 15), bc = lane & 15, k8 = (lane >> 4) * 8;
#pragma unroll
    for (int kk = 0; kk < BK; kk += 32) {
      bf16x8 af = *(const bf16x8*)&a_sh[ar * LDA + kk + k8];
#pragma unroll
      for (int nt = 0; nt < 4; nt++) {
        bf16x8 bf = *(const bf16x8*)&b_sh[(nt * 16 + bc) * LDA + kk + k8];
        acc[nt] = __builtin_amdgcn_mfma_f32_16x16x32_bf16(af, bf, acc[nt], 0, 0, 0);
      }
    }
  }
  const int trow = t0 + wave * 16 + ((lane >> 4) << 2);
#pragma unroll
  for (int nt = 0; nt < 4; nt++) {
    const int n = n0 + nt * 16 + (lane & 15);
#pragma unroll
    for (int j = 0; j < 4; j++)
      out[(size_t)(trow + j) * DHID + n] = acc[nt][j];
  }
}

// ---------------- routed down: out[tok] += h_r[e] @ wd_r[e] (K=256), atomic scatter ----------------
__global__ __launch_bounds__(256) void k_down_routed(
    const ushort* __restrict__ h_r, const ushort* __restrict__ BT,
    const int* __restrict__ cnt, const int* __restrict__ ltok,
    float* __restrict__ out)
{
  __shared__ ushort a_sh[64 * LDA], b_sh[64 * LDA];
  const int e = blockIdx.z;
  const int c = cnt[e];
  const int s0 = blockIdx.x * 64;
  if (s0 >= c) return;
  const int n0 = blockIdx.y * 64;      // over DHID=1024
  const int tid = threadIdx.x, wave = tid >> 6, lane = tid & 63;
  const int srow = tid >> 2, sseg = tid & 3;
  const ushort* Ab = h_r + (size_t)e * CAP * MR + (size_t)s0 * MR;
  const ushort* Bb = BT  + ((size_t)e * DHID + n0) * MR;

  f32x4 acc[4] = {};
  for (int k0 = 0; k0 < MR; k0 += BK) {
    __syncthreads();
    const size_t sa = (size_t)srow * MR + k0;
    *(uint4*)&a_sh[srow * LDA + sseg * 8]       = *(const uint4*)&Ab[sa + sseg * 8];
    *(uint4*)&a_sh[srow * LDA + (sseg + 4) * 8] = *(const uint4*)&Ab[sa + (sseg + 4) * 8];
    *(uint4*)&b_sh[srow * LDA + sseg * 8]       = *(const uint4*)&Bb[sa + sseg * 8];
    *(uint4*)&b_sh[srow * LDA + (sseg + 4) * 8] = *(const uint4*)&Bb[sa + (sseg + 4) * 8];
    __syncthreads();
    const int ar = wave * 16 + (lane & 15), bc = lane & 15, k8 = (lane >> 4) * 8;
#pragma unroll
    for (int kk = 0; kk < BK; kk += 32) {
      bf16x8 af = *(const bf16x8*)&a_sh[ar * LDA + kk + k8];
#pragma unroll
      for (int nt = 0; nt < 4; nt++) {
        bf16x8 bf = *(const bf16x8*)&b_sh[(nt * 16 + bc) * LDA + kk + k8];
        acc[nt] = __builtin_amdgcn_mfma_f32_16x16x32_bf16(af, bf, acc[nt], 0, 0, 0);
      }
    }
  }
  const int bc = lane & 15;
#pragma unroll
  for (int j = 0; j < 4; j++) {
    const int slot = s0 + wave * 16 + ((lane >> 4) << 2) + j;
    if (slot < c) {
      const int t = ltok[e * CAP + slot];
#pragma unroll
      for (int nt = 0; nt < 4; nt++)
        atomicAdd(&out[(size_t)t * DHID + n0 + nt * 16 + bc], acc[nt][j]);
    }
  }
}

extern "C" void kernel_launch(void* const* d_in, const int* in_sizes, int n_in,
                              void* d_out, int out_size, void* d_ws, size_t ws_size,
                              hipStream_t stream) {
  const float* x    = (const float*)d_in[0];
  const float* rw   = (const float*)d_in[1];
  const float* wg_r = (const float*)d_in[2];
  const float* wu_r = (const float*)d_in[3];
  const float* wd_r = (const float*)d_in[4];
  const float* wg_s = (const float*)d_in[5];
  const float* wu_s = (const float*)d_in[6];
  const float* wd_s = (const float*)d_in[7];
  float* out = (float*)d_out;

  char* ws = (char*)d_ws;
  size_t off = 0;
  ushort* xb   = (ushort*)(ws + off); off += (size_t)T_TOK * DHID * 2;      // 4 MB
  ushort* wgTr = (ushort*)(ws + off); off += (size_t)NEXP * MR * DHID * 2;  // 8 MB
  ushort* wuTr = (ushort*)(ws + off); off += (size_t)NEXP * MR * DHID * 2;  // 8 MB
  ushort* wdTr = (ushort*)(ws + off); off += (size_t)NEXP * DHID * MR * 2;  // 8 MB
  ushort* wgTs = (ushort*)(ws + off); off += (size_t)2 * MS * DHID * 2;     // 2 MB
  ushort* wuTs = (ushort*)(ws + off); off += (size_t)2 * MS * DHID * 2;     // 2 MB
  ushort* wdTs = (ushort*)(ws + off); off += (size_t)DHID * DHID * 2;       // 2 MB
  ushort* h_s  = (ushort*)(ws + off); off += (size_t)T_TOK * DHID * 2;      // 4 MB
  ushort* h_r  = (ushort*)(ws + off); off += (size_t)NEXP * CAP * MR * 2;   // 4 MB
  int*    cnt  = (int*)(ws + off);    off += 256;
  int*    ltok = (int*)(ws + off);    off += (size_t)NEXP * CAP * 4;
  float*  lw   = (float*)(ws + off);  off += (size_t)NEXP * CAP * 4;
  int*    topi = (int*)(ws + off);    off += (size_t)T_TOK * 4;
  float2* topw = (float2*)(ws + off); off += (size_t)T_TOK * 8;
  if (off > ws_size) return;  // workspace too small; bail (will show as absmax fail)

  k_prep<<<T_TOK / 4, 256, 0, stream>>>(x, rw, xb, topi, topw);
  k_build<<<NEXP, 256, 0, stream>>>(topi, topw, cnt, ltok, lw);

  // transposed bf16 weights: out[b][n][k]
  k_transpose<<<dim3(MR / 64, DHID / 64, NEXP), 256, 0, stream>>>(wg_r, wgTr, MR,  DHID, (size_t)MR * DHID);
  k_transpose<<<dim3(MR / 64, DHID / 64, NEXP), 256, 0, stream>>>(wu_r, wuTr, MR,  DHID, (size_t)MR * DHID);
  k_transpose<<<dim3(DHID / 64, MR / 64, NEXP), 256, 0, stream>>>(wd_r, wdTr, DHID, MR,  (size_t)DHID * MR);
  k_transpose<<<dim3(MS / 64, DHID / 64, 2),    256, 0, stream>>>(wg_s, wgTs, MS,  DHID, (size_t)MS * DHID);
  k_transpose<<<dim3(MS / 64, DHID / 64, 2),    256, 0, stream>>>(wu_s, wuTs, MS,  DHID, (size_t)MS * DHID);
  // wd_s: [2][512][1024] -> wdTs[n][e*512+m]  (out_ld=1024, batch offset=512 elements)
  k_transpose<<<dim3(DHID / 64, MS / 64, 2),    256, 0, stream>>>(wd_s, wdTs, DHID, DHID, (size_t)MS);

  k_up_shared<<<dim3(T_TOK / 64, (2 * MS) / 64), 256, 0, stream>>>(xb, wgTs, wuTs, h_s);
  k_up_routed<<<dim3(CAP / 64, MR / 64, NEXP),   256, 0, stream>>>(xb, wgTr, wuTr, cnt, ltok, lw, h_r);
  k_down_shared<<<dim3(T_TOK / 64, DHID / 64),   256, 0, stream>>>(h_s, wdTs, out);
  k_down_routed<<<dim3(CAP / 64, DHID / 64, NEXP), 256, 0, stream>>>(h_r, wdTr, cnt, ltok, out);
}

// Round 4
// 115.233 us; speedup vs baseline: 1.6321x; 1.1506x over previous
//
#include <hip/hip_runtime.h>
#include <hip/hip_bf16.h>
#include <stdint.h>

#define T_TOK 2048
#define DHID  1024
#define NEXP  16
#define MR    256
#define MS    512
#define CAP   512   // max tokens per routed expert (mean 256; inputs fixed, verified to fit)

typedef float  f32x4  __attribute__((ext_vector_type(4)));
typedef __bf16 bf16x8 __attribute__((ext_vector_type(8)));

typedef __attribute__((address_space(3))) void       lds_void;
typedef const __attribute__((address_space(1))) void gbl_void;

// async global->LDS, 16B per lane; LDS dest = wave-uniform base + lane*16 (HW rule)
#define GLOAD16(g, l) __builtin_amdgcn_global_load_lds((gbl_void*)(g), (lds_void*)(l), 16, 0, 0)

__device__ __forceinline__ ushort f2bf(float f) {
  uint32_t u = __float_as_uint(f);
  u = (u + 0x7fffu + ((u >> 16) & 1u)) >> 16;
  return (ushort)u;
}
__device__ __forceinline__ float bf2f(ushort v) { return __uint_as_float(((uint32_t)v) << 16); }

// ---- stage a 128x64 bf16 tile (16 KB) from rows of a row-major matrix into linear LDS ----
// thread tid covers LDS bytes [tid*16) of shot s; row = s*32 + tid/8, colE = (tid&7)*8
__device__ __forceinline__ void stage_lin(const ushort* __restrict__ g0, int strideE,
                                          ushort* lds, int tid) {
  const int wave = tid >> 6;
  const int r = tid >> 3, colE = (tid & 7) * 8;
#pragma unroll
  for (int s = 0; s < 4; ++s)
    GLOAD16(g0 + (size_t)(s * 32 + r) * strideE + colE, lds + s * 2048 + wave * 512);
}

// gathered rows from xb (token list), row stride DHID
__device__ __forceinline__ void stage_gather(const ushort* __restrict__ xb,
                                             const int tok[4], int k0,
                                             ushort* lds, int tid) {
  const int wave = tid >> 6;
  const int colE = (tid & 7) * 8;
#pragma unroll
  for (int s = 0; s < 4; ++s)
    GLOAD16(xb + (size_t)tok[s] * DHID + k0 + colE, lds + s * 2048 + wave * 512);
}

// ---- one BK=64 step of the 128x128 tile: wave (wr,wc) computes 64x64 via 4x4 frags ----
__device__ __forceinline__ void mfma_tile(const ushort* a_sh, const ushort* b_sh,
                                          int wr, int wc, int lane, f32x4 (&acc)[4][4]) {
  const int rb = lane & 15;
#pragma unroll
  for (int kk = 0; kk < 64; kk += 32) {
    const int k8 = kk + ((lane >> 4) << 3);
    bf16x8 af[4];
#pragma unroll
    for (int m = 0; m < 4; m++)
      af[m] = *(const bf16x8*)&a_sh[(wr * 64 + m * 16 + rb) * 64 + k8];
#pragma unroll
    for (int n = 0; n < 4; n++) {
      bf16x8 bf = *(const bf16x8*)&b_sh[(wc * 64 + n * 16 + rb) * 64 + k8];
#pragma unroll
      for (int m = 0; m < 4; m++)
        acc[m][n] = __builtin_amdgcn_mfma_f32_16x16x32_bf16(af[m], bf, acc[m][n], 0, 0, 0);
    }
  }
}

// ---------------- x->bf16 + fp32 router; 8 tokens per block ----------------
__global__ __launch_bounds__(256) void k_prep(
    const float* __restrict__ x, const float* __restrict__ rw,
    ushort* __restrict__ xb, int* __restrict__ topi, float2* __restrict__ topw)
{
  __shared__ float rw_sh[NEXP][DHID];   // transposed [e][d]
  const int tid = threadIdx.x;
#pragma unroll
  for (int it = 0; it < 16; ++it) {
    const int flat = it * 1024 + tid * 4;
    float4 v = *(const float4*)&rw[flat];
    const int d = flat >> 4, e = flat & 15;
    rw_sh[e + 0][d] = v.x; rw_sh[e + 1][d] = v.y;
    rw_sh[e + 2][d] = v.z; rw_sh[e + 3][d] = v.w;
  }
  __syncthreads();

  const int wave = tid >> 6, lane = tid & 63;
  for (int tk = 0; tk < 2; ++tk) {
    const int t = blockIdx.x * 8 + wave * 2 + tk;
    const float* xp = x + (size_t)t * DHID;
    float acc[NEXP];
#pragma unroll
    for (int e = 0; e < NEXP; e++) acc[e] = 0.f;
#pragma unroll
    for (int i = 0; i < 4; ++i) {
      const int d4 = i * 64 + lane;             // float4 index, lane-consecutive
      float4 xv = *(const float4*)&xp[d4 * 4];
      ushort4 o; o.x = f2bf(xv.x); o.y = f2bf(xv.y); o.z = f2bf(xv.z); o.w = f2bf(xv.w);
      *(ushort4*)&xb[(size_t)t * DHID + d4 * 4] = o;
#pragma unroll
      for (int e = 0; e < NEXP; e++) {
        float4 wv = *(const float4*)&rw_sh[e][d4 * 4];
        acc[e] = fmaf(xv.x, wv.x, acc[e]);
        acc[e] = fmaf(xv.y, wv.y, acc[e]);
        acc[e] = fmaf(xv.z, wv.z, acc[e]);
        acc[e] = fmaf(xv.w, wv.w, acc[e]);
      }
    }
#pragma unroll
    for (int off = 32; off >= 1; off >>= 1) {
#pragma unroll
      for (int e = 0; e < NEXP; e++) acc[e] += __shfl_xor(acc[e], off, 64);
    }
    if (lane == 0) {
      float m = acc[0];
#pragma unroll
      for (int e = 1; e < NEXP; e++) m = fmaxf(m, acc[e]);
      float p[NEXP], Z = 0.f;
#pragma unroll
      for (int e = 0; e < NEXP; e++) { p[e] = __expf(acc[e] - m); Z += p[e]; }
      const float inv = 1.f / Z;
      int i1 = 0; float p1 = p[0] * inv;
      for (int e = 1; e < NEXP; e++) { float pe = p[e] * inv; if (pe > p1) { p1 = pe; i1 = e; } }
      int i2 = -1; float p2 = -1.f;
      for (int e = 0; e < NEXP; e++) { if (e == i1) continue; float pe = p[e] * inv; if (pe > p2) { p2 = pe; i2 = e; } }
      const float denom = p1 + p2 + 1e-9f;
      topi[t] = i1 | (i2 << 8);
      topw[t] = make_float2(p1 / denom, p2 / denom);
    }
  }
}

// ---------------- per-expert compacted token lists (deterministic, no atomics) ----------------
__global__ __launch_bounds__(256) void k_build(
    const int* __restrict__ topi, const float2* __restrict__ topw,
    int* __restrict__ cnt, int* __restrict__ ltok, float* __restrict__ lw)
{
  __shared__ int wsum[4];
  const int e = blockIdx.x;
  const int tid = threadIdx.x, wave = tid >> 6, lane = tid & 63;
  const int t0 = tid * 8;

  int4 a = *(const int4*)&topi[t0];
  int4 b = *(const int4*)&topi[t0 + 4];
  int ti[8] = {a.x, a.y, a.z, a.w, b.x, b.y, b.z, b.w};
  int match[8]; int c = 0;
#pragma unroll
  for (int k = 0; k < 8; ++k) {
    const int i1 = ti[k] & 0xff, i2 = (ti[k] >> 8) & 0xff;
    match[k] = (i1 == e) ? 1 : ((i2 == e) ? 2 : 0);
    c += (match[k] != 0);
  }
  int incl = c;
#pragma unroll
  for (int off = 1; off < 64; off <<= 1) {
    int n = __shfl_up(incl, off, 64);
    if (lane >= off) incl += n;
  }
  if (lane == 63) wsum[wave] = incl;
  __syncthreads();
  int base = incl - c;
  for (int w = 0; w < wave; ++w) base += wsum[w];
  if (tid == 0) {
    int tot = wsum[0] + wsum[1] + wsum[2] + wsum[3];
    cnt[e] = tot > CAP ? CAP : tot;
  }
#pragma unroll
  for (int k = 0; k < 8; ++k) {
    if (match[k]) {
      if (base < CAP) {
        float2 w2 = topw[t0 + k];
        ltok[e * CAP + base] = t0 + k;
        lw[e * CAP + base] = (match[k] == 1) ? w2.x : w2.y;
      }
      base++;
    }
  }
}

// ---------------- merged transpose+convert: 6 weight matrices, one launch ----------------
struct TP {
  const float* in; ushort* out;
  int R, C, out_ld;
  long long out_batch;
  int end;   // cumulative tile count (exclusive)
};

__global__ __launch_bounds__(256) void k_tpose(TP p0, TP p1, TP p2, TP p3, TP p4, TP p5) {
  const int bid = blockIdx.x;
  TP p; int base;
  if      (bid < p0.end) { p = p0; base = 0; }
  else if (bid < p1.end) { p = p1; base = p0.end; }
  else if (bid < p2.end) { p = p2; base = p1.end; }
  else if (bid < p3.end) { p = p3; base = p2.end; }
  else if (bid < p4.end) { p = p4; base = p3.end; }
  else                   { p = p5; base = p4.end; }
  const int local = bid - base;
  const int tr = p.R >> 6, tc = p.C >> 6, per = tr * tc;
  const int b = local / per, rem = local - b * per;
  const int rt = rem / tc, ct = rem - rt * tc;
  const int r0 = rt * 64, c0 = ct * 64;
  const float* ip = p.in + (size_t)b * p.R * p.C;
  ushort* op = p.out + (size_t)b * p.out_batch;

  __shared__ float t_sh[64][65];
  const int tid = threadIdx.x;
  const int trd = tid >> 4, tcd = (tid & 15) * 4;
#pragma unroll
  for (int q = 0; q < 4; q++) {
    float4 v = *(const float4*)&ip[(size_t)(r0 + trd + q * 16) * p.C + c0 + tcd];
    t_sh[trd + q * 16][tcd + 0] = v.x; t_sh[trd + q * 16][tcd + 1] = v.y;
    t_sh[trd + q * 16][tcd + 2] = v.z; t_sh[trd + q * 16][tcd + 3] = v.w;
  }
  __syncthreads();
#pragma unroll
  for (int q = 0; q < 4; q++) {
    const int cc = trd + q * 16;
    ushort4 o;
    o.x = f2bf(t_sh[tcd + 0][cc]); o.y = f2bf(t_sh[tcd + 1][cc]);
    o.z = f2bf(t_sh[tcd + 2][cc]); o.w = f2bf(t_sh[tcd + 3][cc]);
    *(ushort4*)&op[(size_t)(c0 + cc) * p.out_ld + r0 + tcd] = o;
  }
}

// ---------------- up GEMMs (shared + routed in one launch), plain C = A*B^T ----------------
// blocks [0,256): shared  A=xb[2048][1024], B=wguTs[2048][1024] -> gu_s[2048][2048]
// blocks [256,512): routed per expert, A=gathered xb rows, B=wguTr[e][512][1024] -> gu_r[e][CAP][512]
__global__ __launch_bounds__(256) void k_up(
    const ushort* __restrict__ xb, const ushort* __restrict__ wguTs,
    const ushort* __restrict__ wguTr, const int* __restrict__ cnt,
    const int* __restrict__ ltok, ushort* __restrict__ gu_s, ushort* __restrict__ gu_r)
{
  __shared__ ushort a_sh[128 * 64], b_sh[128 * 64];
  const int tid = threadIdx.x, lane = tid & 63, wave = tid >> 6;
  const int wr = wave >> 1, wc = wave & 1;
  f32x4 acc[4][4] = {};
  const int bid = blockIdx.x;

  if (bid < 256) {
    const int mt = bid & 15, nt = bid >> 4;
    const ushort* Ab = xb + (size_t)mt * 128 * DHID;
    const ushort* Bb = wguTs + (size_t)nt * 128 * DHID;
    for (int k0 = 0; k0 < DHID; k0 += 64) {
      __syncthreads();
      stage_lin(Ab + k0, DHID, a_sh, tid);
      stage_lin(Bb + k0, DHID, b_sh, tid);
      __syncthreads();
      mfma_tile(a_sh, b_sh, wr, wc, lane, acc);
    }
    const int r0 = mt * 128 + wr * 64, c0 = nt * 128 + wc * 64;
#pragma unroll
    for (int m = 0; m < 4; m++)
#pragma unroll
      for (int j = 0; j < 4; j++) {
        const int row = r0 + m * 16 + ((lane >> 4) << 2) + j;
#pragma unroll
        for (int n = 0; n < 4; n++)
          gu_s[(size_t)row * 2048 + c0 + n * 16 + (lane & 15)] = f2bf(acc[m][n][j]);
      }
  } else {
    const int id = bid - 256;
    const int e = id >> 4, st = (id >> 2) & 3, ntile = id & 3;
    const int c = cnt[e], s0 = st * 128;
    if (s0 >= c) return;
    int tok[4];
#pragma unroll
    for (int s = 0; s < 4; ++s) {
      int slot = s0 + s * 32 + (tid >> 3);
      if (slot >= c) slot = c - 1;
      tok[s] = ltok[e * CAP + slot];
    }
    const ushort* Bb = wguTr + ((size_t)e * 512 + ntile * 128) * DHID;
    for (int k0 = 0; k0 < DHID; k0 += 64) {
      __syncthreads();
      stage_gather(xb, tok, k0, a_sh, tid);
      stage_lin(Bb + k0, DHID, b_sh, tid);
      __syncthreads();
      mfma_tile(a_sh, b_sh, wr, wc, lane, acc);
    }
    const int c0 = ntile * 128 + wc * 64;
#pragma unroll
    for (int m = 0; m < 4; m++)
#pragma unroll
      for (int j = 0; j < 4; j++) {
        const int slot = s0 + wr * 64 + m * 16 + ((lane >> 4) << 2) + j;
        if (slot < c) {
#pragma unroll
          for (int n = 0; n < 4; n++)
            gu_r[((size_t)e * CAP + slot) * 512 + c0 + n * 16 + (lane & 15)] = f2bf(acc[m][n][j]);
        }
      }
  }
}

// ---------------- activation epilogue: h = silu(g)*u (*routing weight for routed) ----------------
__global__ __launch_bounds__(256) void k_act(
    const ushort* __restrict__ gu_s, const ushort* __restrict__ gu_r,
    const int* __restrict__ cnt, const float* __restrict__ lw,
    ushort* __restrict__ h_s, ushort* __restrict__ h_r)
{
  const int tid = threadIdx.x;
  const int bid = blockIdx.x;
  if (bid < 1024) {
    const int idx = bid * 2048 + tid * 8;         // into [2048][1024]
    const int t = idx >> 10, m = idx & 1023;
    const ushort* gp = gu_s + (size_t)t * 2048 + m;
    ushort4 g0 = *(const ushort4*)gp,          g1 = *(const ushort4*)(gp + 4);
    ushort4 u0 = *(const ushort4*)(gp + 1024), u1 = *(const ushort4*)(gp + 1028);
    ushort gg[8] = {g0.x, g0.y, g0.z, g0.w, g1.x, g1.y, g1.z, g1.w};
    ushort uu[8] = {u0.x, u0.y, u0.z, u0.w, u1.x, u1.y, u1.z, u1.w};
    ushort o[8];
#pragma unroll
    for (int k = 0; k < 8; ++k) {
      float g = bf2f(gg[k]), u = bf2f(uu[k]);
      o[k] = f2bf((g / (1.f + __expf(-g))) * u);
    }
    *(ushort4*)&h_s[(size_t)t * 1024 + m]     = make_ushort4(o[0], o[1], o[2], o[3]);
    *(ushort4*)&h_s[(size_t)t * 1024 + m + 4] = make_ushort4(o[4], o[5], o[6], o[7]);
  } else {
    const int idx = (bid - 1024) * 2048 + tid * 8;  // into [16][CAP][256]
    const int es = idx >> 8;                        // e*CAP + slot
    const int e = es >> 9, slot = es & (CAP - 1);
    const int m = idx & 255;
    if (slot < cnt[e]) {
      const float w = lw[es];
      const ushort* gp = gu_r + (size_t)es * 512 + m;
      ushort4 g0 = *(const ushort4*)gp,         g1 = *(const ushort4*)(gp + 4);
      ushort4 u0 = *(const ushort4*)(gp + 256), u1 = *(const ushort4*)(gp + 260);
      ushort gg[8] = {g0.x, g0.y, g0.z, g0.w, g1.x, g1.y, g1.z, g1.w};
      ushort uu[8] = {u0.x, u0.y, u0.z, u0.w, u1.x, u1.y, u1.z, u1.w};
      ushort o[8];
#pragma unroll
      for (int k = 0; k < 8; ++k) {
        float g = bf2f(gg[k]), u = bf2f(uu[k]);
        o[k] = f2bf((g / (1.f + __expf(-g))) * u * w);
      }
      *(ushort4*)&h_r[(size_t)es * 256 + m]     = make_ushort4(o[0], o[1], o[2], o[3]);
      *(ushort4*)&h_r[(size_t)es * 256 + m + 4] = make_ushort4(o[4], o[5], o[6], o[7]);
    }
  }
}

// ---------------- shared down: out = h_s @ wdTs^T, plain f32 stores ----------------
__global__ __launch_bounds__(256) void k_down_s(
    const ushort* __restrict__ h_s, const ushort* __restrict__ wdTs,
    float* __restrict__ out)
{
  __shared__ ushort a_sh[128 * 64], b_sh[128 * 64];
  const int tid = threadIdx.x, lane = tid & 63, wave = tid >> 6;
  const int wr = wave >> 1, wc = wave & 1;
  const int mt = blockIdx.x & 15, nt = blockIdx.x >> 4;
  f32x4 acc[4][4] = {};
  const ushort* Ab = h_s + (size_t)mt * 128 * DHID;
  const ushort* Bb = wdTs + (size_t)nt * 128 * DHID;
  for (int k0 = 0; k0 < DHID; k0 += 64) {
    __syncthreads();
    stage_lin(Ab + k0, DHID, a_sh, tid);
    stage_lin(Bb + k0, DHID, b_sh, tid);
    __syncthreads();
    mfma_tile(a_sh, b_sh, wr, wc, lane, acc);
  }
  const int r0 = mt * 128 + wr * 64, c0 = nt * 128 + wc * 64;
#pragma unroll
  for (int m = 0; m < 4; m++)
#pragma unroll
    for (int j = 0; j < 4; j++) {
      const int row = r0 + m * 16 + ((lane >> 4) << 2) + j;
#pragma unroll
      for (int n = 0; n < 4; n++)
        out[(size_t)row * DHID + c0 + n * 16 + (lane & 15)] = acc[m][n][j];
    }
}

// ---------------- routed down: out[tok] += h_r[e] @ wdTr[e]^T (K=256), atomic scatter ----------------
__global__ __launch_bounds__(256) void k_down_r(
    const ushort* __restrict__ h_r, const ushort* __restrict__ wdTr,
    const int* __restrict__ cnt, const int* __restrict__ ltok,
    float* __restrict__ out)
{
  __shared__ ushort a_sh[128 * 64], b_sh[128 * 64];
  const int tid = threadIdx.x, lane = tid & 63, wave = tid >> 6;
  const int wr = wave >> 1, wc = wave & 1;
  const int bid = blockIdx.x;
  const int e = bid >> 5, st = (bid >> 3) & 3, nt = bid & 7;
  const int c = cnt[e], s0 = st * 128;
  if (s0 >= c) return;
  f32x4 acc[4][4] = {};
  const ushort* Ab = h_r + ((size_t)e * CAP + s0) * MR;
  const ushort* Bb = wdTr + ((size_t)e * DHID + nt * 128) * MR;
  for (int k0 = 0; k0 < MR; k0 += 64) {
    __syncthreads();
    stage_lin(Ab + k0, MR, a_sh, tid);
    stage_lin(Bb + k0, MR, b_sh, tid);
    __syncthreads();
    mfma_tile(a_sh, b_sh, wr, wc, lane, acc);
  }
  const int c0 = nt * 128 + wc * 64;
#pragma unroll
  for (int m = 0; m < 4; m++)
#pragma unroll
    for (int j = 0; j < 4; j++) {
      const int slot = s0 + wr * 64 + m * 16 + ((lane >> 4) << 2) + j;
      if (slot < c) {
        const int t = ltok[e * CAP + slot];
#pragma unroll
        for (int n = 0; n < 4; n++)
          atomicAdd(&out[(size_t)t * DHID + c0 + n * 16 + (lane & 15)], acc[m][n][j]);
      }
    }
}

extern "C" void kernel_launch(void* const* d_in, const int* in_sizes, int n_in,
                              void* d_out, int out_size, void* d_ws, size_t ws_size,
                              hipStream_t stream) {
  const float* x    = (const float*)d_in[0];
  const float* rw   = (const float*)d_in[1];
  const float* wg_r = (const float*)d_in[2];
  const float* wu_r = (const float*)d_in[3];
  const float* wd_r = (const float*)d_in[4];
  const float* wg_s = (const float*)d_in[5];
  const float* wu_s = (const float*)d_in[6];
  const float* wd_s = (const float*)d_in[7];
  float* out = (float*)d_out;

  char* ws = (char*)d_ws;
  size_t off = 0;
  ushort* xb    = (ushort*)(ws + off); off += (size_t)T_TOK * DHID * 2;        // 4 MB
  ushort* wguTs = (ushort*)(ws + off); off += (size_t)2048 * DHID * 2;         // 4 MB  [g(1024) | u(1024)][k]
  ushort* wdTs  = (ushort*)(ws + off); off += (size_t)DHID * DHID * 2;         // 2 MB  [d][mcat]
  ushort* wguTr = (ushort*)(ws + off); off += (size_t)NEXP * 512 * DHID * 2;   // 16 MB [e][g(256)|u(256)][k]
  ushort* wdTr  = (ushort*)(ws + off); off += (size_t)NEXP * DHID * MR * 2;    // 8 MB  [e][d][m]
  ushort* gu_s  = (ushort*)(ws + off); off += (size_t)T_TOK * 2048 * 2;        // 8 MB
  ushort* gu_r  = (ushort*)(ws + off); off += (size_t)NEXP * CAP * 512 * 2;    // 8 MB
  ushort* h_s   = (ushort*)(ws + off); off += (size_t)T_TOK * DHID * 2;        // 4 MB
  ushort* h_r   = (ushort*)(ws + off); off += (size_t)NEXP * CAP * MR * 2;     // 4 MB
  int*    cnt   = (int*)(ws + off);    off += 256;
  int*    ltok  = (int*)(ws + off);    off += (size_t)NEXP * CAP * 4;
  float*  lw    = (float*)(ws + off);  off += (size_t)NEXP * CAP * 4;
  int*    topi  = (int*)(ws + off);    off += (size_t)T_TOK * 4;
  float2* topw  = (float2*)(ws + off); off += (size_t)T_TOK * 8;
  if (off > ws_size) return;

  k_prep<<<T_TOK / 8, 256, 0, stream>>>(x, rw, xb, topi, topw);
  k_build<<<NEXP, 256, 0, stream>>>(topi, topw, cnt, ltok, lw);

  // merged transposes: out elem = b*out_batch + c*out_ld + r
  TP p0 = {wg_r, wguTr,                 DHID, MR,   DHID, (long long)512 * DHID, 1024};
  TP p1 = {wu_r, wguTr + 256 * DHID,    DHID, MR,   DHID, (long long)512 * DHID, 2048};
  TP p2 = {wd_r, wdTr,                  MR,   DHID, MR,   (long long)DHID * MR,  3072};
  TP p3 = {wg_s, wguTs,                 DHID, MS,   DHID, (long long)MS * DHID,  3328};
  TP p4 = {wu_s, wguTs + 1024 * DHID,   DHID, MS,   DHID, (long long)MS * DHID,  3584};
  TP p5 = {wd_s, wdTs,                  MS,   DHID, DHID, (long long)MS,         3840};
  k_tpose<<<3840, 256, 0, stream>>>(p0, p1, p2, p3, p4, p5);

  k_up<<<512, 256, 0, stream>>>(xb, wguTs, wguTr, cnt, ltok, gu_s, gu_r);
  k_act<<<2048, 256, 0, stream>>>(gu_s, gu_r, cnt, lw, h_s, h_r);
  k_down_s<<<128, 256, 0, stream>>>(h_s, wdTs, out);
  k_down_r<<<512, 256, 0, stream>>>(h_r, wdTr, cnt, ltok, out);
}

// Round 5
// 103.884 us; speedup vs baseline: 1.8104x; 1.1093x over previous
//
#include <hip/hip_runtime.h>
#include <hip/hip_bf16.h>
#include <stdint.h>

#define T_TOK 2048
#define DHID  1024
#define NEXP  16
#define MR    256
#define MS    512
#define CAP   512

typedef float  f32x4  __attribute__((ext_vector_type(4)));
typedef __bf16 bf16x8 __attribute__((ext_vector_type(8)));

typedef __attribute__((address_space(3))) void       lds_void;
typedef const __attribute__((address_space(1))) void gbl_void;

#define GLOAD16(g, l) __builtin_amdgcn_global_load_lds((gbl_void*)(g), (lds_void*)(l), 16, 0, 0)

__device__ __forceinline__ ushort f2bf(float f) {
  uint32_t u = __float_as_uint(f);
  u = (u + 0x7fffu + ((u >> 16) & 1u)) >> 16;
  return (ushort)u;
}
__device__ __forceinline__ float bf2f(ushort v) { return __uint_as_float(((uint32_t)v) << 16); }

// ---- stage 128x64 bf16 tile (16 KB) from row-major global into linear LDS ----
__device__ __forceinline__ void stage_lin(const ushort* __restrict__ g0, int strideE,
                                          ushort* lds, int tid) {
  const int wave = tid >> 6;
  const int r = tid >> 3, colE = (tid & 7) * 8;
#pragma unroll
  for (int s = 0; s < 4; ++s)
    GLOAD16(g0 + (size_t)(s * 32 + r) * strideE + colE, lds + s * 2048 + wave * 512);
}

__device__ __forceinline__ void stage_gather(const ushort* __restrict__ xb,
                                             const int tok[4], int k0,
                                             ushort* lds, int tid) {
  const int wave = tid >> 6;
  const int colE = (tid & 7) * 8;
#pragma unroll
  for (int s = 0; s < 4; ++s)
    GLOAD16(xb + (size_t)tok[s] * DHID + k0 + colE, lds + s * 2048 + wave * 512);
}

// ---- one BK=64 step: wave (wr,wc) computes 64x64 via 4x4 16x16 frags ----
__device__ __forceinline__ void mfma_tile(const ushort* a_sh, const ushort* b_sh,
                                          int wr, int wc, int lane, f32x4 (&acc)[4][4]) {
  const int rb = lane & 15;
#pragma unroll
  for (int kk = 0; kk < 64; kk += 32) {
    const int k8 = kk + ((lane >> 4) << 3);
    bf16x8 af[4];
#pragma unroll
    for (int m = 0; m < 4; m++)
      af[m] = *(const bf16x8*)&a_sh[(wr * 64 + m * 16 + rb) * 64 + k8];
#pragma unroll
    for (int n = 0; n < 4; n++) {
      bf16x8 bf = *(const bf16x8*)&b_sh[(wc * 64 + n * 16 + rb) * 64 + k8];
#pragma unroll
      for (int m = 0; m < 4; m++)
        acc[m][n] = __builtin_amdgcn_mfma_f32_16x16x32_bf16(af[m], bf, acc[m][n], 0, 0, 0);
    }
  }
}

// ---------------- x->bf16 + fp32 router; 16 tokens per block ----------------
__global__ __launch_bounds__(256) void k_prep(
    const float* __restrict__ x, const float* __restrict__ rw,
    ushort* __restrict__ xb, int* __restrict__ topi, float2* __restrict__ topw)
{
  __shared__ float rw_sh[NEXP][DHID];
  const int tid = threadIdx.x;
#pragma unroll
  for (int it = 0; it < 16; ++it) {
    const int flat = it * 1024 + tid * 4;
    float4 v = *(const float4*)&rw[flat];
    const int d = flat >> 4, e = flat & 15;
    rw_sh[e + 0][d] = v.x; rw_sh[e + 1][d] = v.y;
    rw_sh[e + 2][d] = v.z; rw_sh[e + 3][d] = v.w;
  }
  __syncthreads();

  const int wave = tid >> 6, lane = tid & 63;
  for (int tk = 0; tk < 4; ++tk) {
    const int t = blockIdx.x * 16 + wave * 4 + tk;
    const float* xp = x + (size_t)t * DHID;
    float acc[NEXP];
#pragma unroll
    for (int e = 0; e < NEXP; e++) acc[e] = 0.f;
#pragma unroll
    for (int i = 0; i < 4; ++i) {
      const int d4 = i * 64 + lane;
      float4 xv = *(const float4*)&xp[d4 * 4];
      ushort4 o; o.x = f2bf(xv.x); o.y = f2bf(xv.y); o.z = f2bf(xv.z); o.w = f2bf(xv.w);
      *(ushort4*)&xb[(size_t)t * DHID + d4 * 4] = o;
#pragma unroll
      for (int e = 0; e < NEXP; e++) {
        float4 wv = *(const float4*)&rw_sh[e][d4 * 4];
        acc[e] = fmaf(xv.x, wv.x, acc[e]);
        acc[e] = fmaf(xv.y, wv.y, acc[e]);
        acc[e] = fmaf(xv.z, wv.z, acc[e]);
        acc[e] = fmaf(xv.w, wv.w, acc[e]);
      }
    }
#pragma unroll
    for (int off = 32; off >= 1; off >>= 1) {
#pragma unroll
      for (int e = 0; e < NEXP; e++) acc[e] += __shfl_xor(acc[e], off, 64);
    }
    if (lane == 0) {
      float m = acc[0];
#pragma unroll
      for (int e = 1; e < NEXP; e++) m = fmaxf(m, acc[e]);
      float p[NEXP], Z = 0.f;
#pragma unroll
      for (int e = 0; e < NEXP; e++) { p[e] = __expf(acc[e] - m); Z += p[e]; }
      const float inv = 1.f / Z;
      int i1 = 0; float p1 = p[0] * inv;
      for (int e = 1; e < NEXP; e++) { float pe = p[e] * inv; if (pe > p1) { p1 = pe; i1 = e; } }
      int i2 = -1; float p2 = -1.f;
      for (int e = 0; e < NEXP; e++) { if (e == i1) continue; float pe = p[e] * inv; if (pe > p2) { p2 = pe; i2 = e; } }
      const float denom = p1 + p2 + 1e-9f;
      topi[t] = i1 | (i2 << 8);
      topw[t] = make_float2(p1 / denom, p2 / denom);
    }
  }
}

// ---------------- per-expert compacted lists + token->slot map (no atomics) ----------------
__global__ __launch_bounds__(256) void k_build(
    const int* __restrict__ topi, const float2* __restrict__ topw,
    int* __restrict__ cnt, int* __restrict__ ltok, float* __restrict__ lw,
    int* __restrict__ tslot)
{
  __shared__ int wsum[4];
  const int e = blockIdx.x;
  const int tid = threadIdx.x, wave = tid >> 6, lane = tid & 63;
  const int t0 = tid * 8;

  int4 a = *(const int4*)&topi[t0];
  int4 b = *(const int4*)&topi[t0 + 4];
  int ti[8] = {a.x, a.y, a.z, a.w, b.x, b.y, b.z, b.w};
  int match[8]; int c = 0;
#pragma unroll
  for (int k = 0; k < 8; ++k) {
    const int i1 = ti[k] & 0xff, i2 = (ti[k] >> 8) & 0xff;
    match[k] = (i1 == e) ? 1 : ((i2 == e) ? 2 : 0);
    c += (match[k] != 0);
  }
  int incl = c;
#pragma unroll
  for (int off = 1; off < 64; off <<= 1) {
    int n = __shfl_up(incl, off, 64);
    if (lane >= off) incl += n;
  }
  if (lane == 63) wsum[wave] = incl;
  __syncthreads();
  int base = incl - c;
  for (int w = 0; w < wave; ++w) base += wsum[w];
  if (tid == 0) {
    int tot = wsum[0] + wsum[1] + wsum[2] + wsum[3];
    cnt[e] = tot > CAP ? CAP : tot;
  }
#pragma unroll
  for (int k = 0; k < 8; ++k) {
    if (match[k]) {
      const int t = t0 + k;
      if (base < CAP) {
        float2 w2 = topw[t];
        ltok[e * CAP + base] = t;
        lw[e * CAP + base] = (match[k] == 1) ? w2.x : w2.y;
        tslot[t * 2 + (match[k] - 1)] = e * CAP + base;
      } else {
        tslot[t * 2 + (match[k] - 1)] = -1;
      }
      base++;
    }
  }
}

// ---------------- merged transpose+convert (6 mats), optional 16-row g/u interleave ----------------
struct TP {
  const float* in; ushort* out;
  int R, C, out_ld, ilv;
  long long out_batch;
  int end;
};

__global__ __launch_bounds__(256) void k_tpose(TP p0, TP p1, TP p2, TP p3, TP p4, TP p5) {
  const int bid = blockIdx.x;
  TP p; int base;
  if      (bid < p0.end) { p = p0; base = 0; }
  else if (bid < p1.end) { p = p1; base = p0.end; }
  else if (bid < p2.end) { p = p2; base = p1.end; }
  else if (bid < p3.end) { p = p3; base = p2.end; }
  else if (bid < p4.end) { p = p4; base = p3.end; }
  else                   { p = p5; base = p4.end; }
  const int local = bid - base;
  const int tr = p.R >> 6, tc = p.C >> 6, per = tr * tc;
  const int b = local / per, rem = local - b * per;
  const int rt = rem / tc, ct = rem - rt * tc;
  const int r0 = rt * 64, c0 = ct * 64;
  const float* ip = p.in + (size_t)b * p.R * p.C;
  ushort* op = p.out + (size_t)b * p.out_batch;

  __shared__ float t_sh[64][65];
  const int tid = threadIdx.x;
  const int trd = tid >> 4, tcd = (tid & 15) * 4;
#pragma unroll
  for (int q = 0; q < 4; q++) {
    float4 v = *(const float4*)&ip[(size_t)(r0 + trd + q * 16) * p.C + c0 + tcd];
    t_sh[trd + q * 16][tcd + 0] = v.x; t_sh[trd + q * 16][tcd + 1] = v.y;
    t_sh[trd + q * 16][tcd + 2] = v.z; t_sh[trd + q * 16][tcd + 3] = v.w;
  }
  __syncthreads();
#pragma unroll
  for (int q = 0; q < 4; q++) {
    const int cc = trd + q * 16;
    int rr = c0 + cc;
    if (p.ilv) rr = ((rr >> 4) << 5) + (rr & 15);   // 16-row g/u interleave slot
    ushort4 o;
    o.x = f2bf(t_sh[tcd + 0][cc]); o.y = f2bf(t_sh[tcd + 1][cc]);
    o.z = f2bf(t_sh[tcd + 2][cc]); o.w = f2bf(t_sh[tcd + 3][cc]);
    *(ushort4*)&op[(size_t)rr * p.out_ld + r0 + tcd] = o;
  }
}

// ---------------- up GEMMs + fused silu*u epilogue ----------------
// B rows interleaved: [16 g-rows | 16 u-rows] per m16-block -> acc n-even=g, n-odd=u.
// blocks [0,256): shared (M=2048, Nrows=2048 -> h cols 1024)
// blocks [256,512): routed e/st/ntile (Nrows=512 -> h cols 256), h *= lw (0 if slot>=c)
__global__ __launch_bounds__(256) void k_up(
    const ushort* __restrict__ xb, const ushort* __restrict__ wguTs,
    const ushort* __restrict__ wguTr, const int* __restrict__ cnt,
    const int* __restrict__ ltok, const float* __restrict__ lw,
    ushort* __restrict__ h_s, ushort* __restrict__ h_r)
{
  __shared__ ushort a_sh[128 * 64], b_sh[128 * 64];
  __shared__ ushort r_sh[128][64];
  const int tid = threadIdx.x, lane = tid & 63, wave = tid >> 6;
  const int wr = wave >> 1, wc = wave & 1;
  const int rb = lane & 15, rowoff = (lane >> 4) << 2;
  f32x4 acc[4][4] = {};
  const int bid = blockIdx.x;

  if (bid < 256) {
    const int mt = bid & 15, nt = bid >> 4;
    const ushort* Ab = xb + (size_t)mt * 128 * DHID;
    const ushort* Bb = wguTs + (size_t)nt * 128 * DHID;
    for (int k0 = 0; k0 < DHID; k0 += 64) {
      __syncthreads();
      stage_lin(Ab + k0, DHID, a_sh, tid);
      stage_lin(Bb + k0, DHID, b_sh, tid);
      __syncthreads();
      mfma_tile(a_sh, b_sh, wr, wc, lane, acc);
    }
    __syncthreads();
#pragma unroll
    for (int m = 0; m < 4; m++)
#pragma unroll
      for (int p = 0; p < 2; p++) {
        f32x4 g = acc[m][2 * p], u = acc[m][2 * p + 1];
#pragma unroll
        for (int jj = 0; jj < 4; jj++) {
          float gv = g[jj];
          float hv = (gv / (1.f + __expf(-gv))) * u[jj];
          r_sh[wr * 64 + m * 16 + rowoff + jj][wc * 32 + p * 16 + rb] = f2bf(hv);
        }
      }
    __syncthreads();
    // coalesced store: h_s rows mt*128.., cols nt*64..
#pragma unroll
    for (int sp = 0; sp < 4; sp++) {
      const int row = sp * 32 + (tid >> 3), col = (tid & 7) * 8;
      *(uint4*)&h_s[(size_t)(mt * 128 + row) * DHID + nt * 64 + col] = *(const uint4*)&r_sh[row][col];
    }
  } else {
    const int id = bid - 256;
    const int e = id >> 4, st = (id >> 2) & 3, ntile = id & 3;
    const int c = cnt[e], s0 = st * 128;
    if (s0 >= c) return;
    int tok[4];
#pragma unroll
    for (int s = 0; s < 4; ++s) {
      int slot = s0 + s * 32 + (tid >> 3);
      if (slot >= c) slot = c - 1;
      tok[s] = ltok[e * CAP + slot];
    }
    const ushort* Bb = wguTr + ((size_t)e * 512 + ntile * 128) * DHID;
    for (int k0 = 0; k0 < DHID; k0 += 64) {
      __syncthreads();
      stage_gather(xb, tok, k0, a_sh, tid);
      stage_lin(Bb + k0, DHID, b_sh, tid);
      __syncthreads();
      mfma_tile(a_sh, b_sh, wr, wc, lane, acc);
    }
    __syncthreads();
#pragma unroll
    for (int m = 0; m < 4; m++) {
#pragma unroll
      for (int jj = 0; jj < 4; jj++) {
        const int slot = s0 + wr * 64 + m * 16 + rowoff + jj;
        const float w = (slot < c) ? lw[e * CAP + slot] : 0.f;
#pragma unroll
        for (int p = 0; p < 2; p++) {
          float gv = acc[m][2 * p][jj];
          float hv = (gv / (1.f + __expf(-gv))) * acc[m][2 * p + 1][jj] * w;
          r_sh[wr * 64 + m * 16 + rowoff + jj][wc * 32 + p * 16 + rb] = f2bf(hv);
        }
      }
    }
    __syncthreads();
#pragma unroll
    for (int sp = 0; sp < 4; sp++) {
      const int row = sp * 32 + (tid >> 3), col = (tid & 7) * 8;
      *(uint4*)&h_r[((size_t)e * CAP + s0 + row) * MR + ntile * 64 + col] = *(const uint4*)&r_sh[row][col];
    }
  }
}

// ---------------- down GEMMs (merged): bf16 partials, no atomics ----------------
// bid<128: shared  ds[t][d] = h_s @ wdTs^T (K=1024)
// else: routed dr[e][slot][d] = h_r[e] @ wdTr[e]^T (K=256)
__global__ __launch_bounds__(256) void k_down(
    const ushort* __restrict__ h_s, const ushort* __restrict__ wdTs,
    const ushort* __restrict__ h_r, const ushort* __restrict__ wdTr,
    const int* __restrict__ cnt, ushort* __restrict__ ds, ushort* __restrict__ dr)
{
  __shared__ ushort a_sh[128 * 64], b_sh[128 * 64];
  __shared__ ushort r_sh[128][64];
  const int tid = threadIdx.x, lane = tid & 63, wave = tid >> 6;
  const int wr = wave >> 1, wc = wave & 1;
  const int rb = lane & 15, rowoff = (lane >> 4) << 2;
  f32x4 acc[4][4] = {};
  const int bid = blockIdx.x;

  const ushort* Ab; const ushort* Bb;
  int K, rowbase, colbase; ushort* outp; int out_ld;
  if (bid < 128) {
    const int mt = bid >> 3, nt = bid & 7;
    Ab = h_s + (size_t)mt * 128 * DHID;
    Bb = wdTs + (size_t)nt * 128 * DHID;
    K = DHID; rowbase = mt * 128; colbase = nt * 128;
    outp = ds; out_ld = DHID;
  } else {
    const int id = bid - 128;
    const int e = id >> 5, st = (id >> 3) & 3, nt = id & 7;
    const int c = cnt[e], s0 = st * 128;
    if (s0 >= c) return;
    Ab = h_r + ((size_t)e * CAP + s0) * MR;
    Bb = wdTr + ((size_t)e * DHID + nt * 128) * MR;
    K = MR; rowbase = e * CAP + s0; colbase = nt * 128;
    outp = dr; out_ld = DHID;
  }
  const int strideA = K, strideB = K;
  for (int k0 = 0; k0 < K; k0 += 64) {
    __syncthreads();
    stage_lin(Ab + k0, strideA, a_sh, tid);
    stage_lin(Bb + k0, strideB, b_sh, tid);
    __syncthreads();
    mfma_tile(a_sh, b_sh, wr, wc, lane, acc);
  }
  // two repack passes of 64 cols (compressed col = wc*32 + (n&1)*16 + rb for n in {2p,2p+1})
#pragma unroll
  for (int p = 0; p < 2; p++) {
    __syncthreads();
#pragma unroll
    for (int m = 0; m < 4; m++)
#pragma unroll
      for (int h = 0; h < 2; h++) {
        f32x4 v = acc[m][2 * p + h];
#pragma unroll
        for (int jj = 0; jj < 4; jj++)
          r_sh[wr * 64 + m * 16 + rowoff + jj][wc * 32 + h * 16 + rb] = f2bf(v[jj]);
      }
    __syncthreads();
#pragma unroll
    for (int sp = 0; sp < 4; sp++) {
      const int row = sp * 32 + (tid >> 3), cc = (tid & 7) * 8;
      const int gcol = colbase + (cc >> 5) * 64 + p * 32 + (cc & 31);
      *(uint4*)&outp[(size_t)(rowbase + row) * out_ld + gcol] = *(const uint4*)&r_sh[row][cc];
    }
  }
}

// ---------------- combine: out[t] = ds[t] + dr[es1] + dr[es2]  (f32 out) ----------------
__global__ __launch_bounds__(256) void k_comb(
    const ushort* __restrict__ ds, const ushort* __restrict__ dr,
    const int* __restrict__ tslot, float* __restrict__ out)
{
  const int tid = threadIdx.x;
  const int t = blockIdx.x * 2 + (tid >> 7);
  const int d = (tid & 127) * 8;
  const int es1 = tslot[t * 2], es2 = tslot[t * 2 + 1];
  uint4 a = *(const uint4*)&ds[(size_t)t * DHID + d];
  float r[8];
  const ushort* ap = (const ushort*)&a;
#pragma unroll
  for (int k = 0; k < 8; ++k) r[k] = bf2f(ap[k]);
  if (es1 >= 0) {
    uint4 b = *(const uint4*)&dr[(size_t)es1 * DHID + d];
    const ushort* bp = (const ushort*)&b;
#pragma unroll
    for (int k = 0; k < 8; ++k) r[k] += bf2f(bp[k]);
  }
  if (es2 >= 0) {
    uint4 b = *(const uint4*)&dr[(size_t)es2 * DHID + d];
    const ushort* bp = (const ushort*)&b;
#pragma unroll
    for (int k = 0; k < 8; ++k) r[k] += bf2f(bp[k]);
  }
  float4* op = (float4*)&out[(size_t)t * DHID + d];
  op[0] = make_float4(r[0], r[1], r[2], r[3]);
  op[1] = make_float4(r[4], r[5], r[6], r[7]);
}

extern "C" void kernel_launch(void* const* d_in, const int* in_sizes, int n_in,
                              void* d_out, int out_size, void* d_ws, size_t ws_size,
                              hipStream_t stream) {
  const float* x    = (const float*)d_in[0];
  const float* rw   = (const float*)d_in[1];
  const float* wg_r = (const float*)d_in[2];
  const float* wu_r = (const float*)d_in[3];
  const float* wd_r = (const float*)d_in[4];
  const float* wg_s = (const float*)d_in[5];
  const float* wu_s = (const float*)d_in[6];
  const float* wd_s = (const float*)d_in[7];
  float* out = (float*)d_out;

  char* ws = (char*)d_ws;
  size_t off = 0;
  ushort* xb    = (ushort*)(ws + off); off += (size_t)T_TOK * DHID * 2;        // 4 MB
  ushort* wguTs = (ushort*)(ws + off); off += (size_t)2048 * DHID * 2;         // 4 MB  interleaved g/u rows
  ushort* wdTs  = (ushort*)(ws + off); off += (size_t)DHID * DHID * 2;         // 2 MB
  ushort* wguTr = (ushort*)(ws + off); off += (size_t)NEXP * 512 * DHID * 2;   // 16 MB interleaved per expert
  ushort* wdTr  = (ushort*)(ws + off); off += (size_t)NEXP * DHID * MR * 2;    // 8 MB
  ushort* h_s   = (ushort*)(ws + off); off += (size_t)T_TOK * DHID * 2;        // 4 MB
  ushort* h_r   = (ushort*)(ws + off); off += (size_t)NEXP * CAP * MR * 2;     // 4 MB
  ushort* ds    = (ushort*)(ws + off); off += (size_t)T_TOK * DHID * 2;        // 4 MB
  ushort* dr    = (ushort*)(ws + off); off += (size_t)NEXP * CAP * DHID * 2;   // 16 MB
  int*    cnt   = (int*)(ws + off);    off += 256;
  int*    ltok  = (int*)(ws + off);    off += (size_t)NEXP * CAP * 4;
  float*  lw    = (float*)(ws + off);  off += (size_t)NEXP * CAP * 4;
  int*    topi  = (int*)(ws + off);    off += (size_t)T_TOK * 4;
  float2* topw  = (float2*)(ws + off); off += (size_t)T_TOK * 8;
  int*    tslot = (int*)(ws + off);    off += (size_t)T_TOK * 2 * 4;
  if (off > ws_size) return;

  k_prep<<<T_TOK / 16, 256, 0, stream>>>(x, rw, xb, topi, topw);
  k_build<<<NEXP, 256, 0, stream>>>(topi, topw, cnt, ltok, lw, tslot);

  TP p0 = {wg_r, wguTr,             DHID, MR,   DHID, 1, (long long)512 * DHID,  1024};
  TP p1 = {wu_r, wguTr + 16 * DHID, DHID, MR,   DHID, 1, (long long)512 * DHID,  2048};
  TP p2 = {wd_r, wdTr,              MR,   DHID, MR,   0, (long long)DHID * MR,   3072};
  TP p3 = {wg_s, wguTs,             DHID, MS,   DHID, 1, (long long)1024 * DHID, 3328};
  TP p4 = {wu_s, wguTs + 16 * DHID, DHID, MS,   DHID, 1, (long long)1024 * DHID, 3584};
  TP p5 = {wd_s, wdTs,              MS,   DHID, DHID, 0, (long long)MS,          3840};
  k_tpose<<<3840, 256, 0, stream>>>(p0, p1, p2, p3, p4, p5);

  k_up<<<512, 256, 0, stream>>>(xb, wguTs, wguTr, cnt, ltok, lw, h_s, h_r);
  k_down<<<640, 256, 0, stream>>>(h_s, wdTs, h_r, wdTr, cnt, ds, dr);
  k_comb<<<T_TOK / 2, 256, 0, stream>>>(ds, dr, tslot, out);
}